// Round 3
// baseline (1712.480 us; speedup 1.0000x reference)
//
#include <hip/hip_runtime.h>

// VectorQuantizer: x [8,16,256,256] fp32 -> N=32768 rows, D=256; codebook K=4096 x 256.
// d_out flat (read back as float32):
//   [0 .. 8388608)   z_q_st  (= codebook[argmin])
//   [8388608]        loss = 1.25 * mean((z_q - x)^2)
//   [8388609 ..)     encoding indices, written as float values
//
// KEY NUMERICS: codebook ~ U(-1/4096, 1/4096) => distances = z_sq (~256) +- ~9e-3.
// In the np fp32 reference, e_sq (~5e-6) is absorbed below half-ulp(z_sq), and the
// final fp32 subtract quantizes at ulp(z_sq) ~ 1.5e-5..3.05e-5, creating bin-ties
// broken by FIRST INDEX. We emulate: fp32 GEMM screen (metric -2*dot = np's
// pre-quantization order), flag rows with top-2 gap <= 3.6e-5, then rescan flagged
// rows with np's quantized metric fl32(z_sq - fl32(2*dot_fp64)), first-index tiebreak.
#define DIMD 256
#define KCODES 4096
#define MT 128
#define KT 128
#define DK 32
#define LSTR 130
#define OUT_LOSS 8388608
#define OUT_IDX  8388609
#define FLAG_EPS 3.6e-5f   // ulp at 512^- (3.05e-5) + margin; over-flagging is harmless

// ws layout (bytes): [0..4) loss f32 | [32..36) wcount i32 | [4096..) wlist i32[cap]

__global__ void init_kernel(float* __restrict__ loss_acc, int* __restrict__ wcount) {
    if (threadIdx.x == 0) { loss_acc[0] = 0.0f; wcount[0] = 0; }
}

__global__ __launch_bounds__(256) void vq_main_kernel(const float* __restrict__ x,
                                                      const float* __restrict__ cb,
                                                      float* __restrict__ out,
                                                      float* __restrict__ loss_acc,
                                                      int* __restrict__ wcount,
                                                      int* __restrict__ wlist,
                                                      int wcap) {
    __shared__ float As[DK * LSTR];       // transposed: As[d*LSTR + row]
    __shared__ float Bs[DK * LSTR];       // transposed: Bs[d*LSTR + code]
    __shared__ float red_d[MT * 17];
    __shared__ float red_2[MT * 17];
    __shared__ int   red_i[MT * 17];
    __shared__ int   widx[MT];
    __shared__ float wpart[4];

    const int tid = threadIdx.x;
    const int tx = tid & 15;              // code-group (8 codes)
    const int ty = tid >> 4;              // row-group (8 rows)
    const float* xblk = x + (size_t)blockIdx.x * MT * DIMD;

    float b1[8], b2[8];
    int   i1[8];
    #pragma unroll
    for (int i = 0; i < 8; ++i) { b1[i] = 3.4e38f; b2[i] = 3.4e38f; i1[i] = 0; }

    const int sr = tid >> 3;              // staging row 0..31
    const int sd = (tid & 7) * 4;         // staging d offset

    for (int kt = 0; kt < KCODES; kt += KT) {
        float acc[8][8];
        #pragma unroll
        for (int i = 0; i < 8; ++i)
            #pragma unroll
            for (int j = 0; j < 8; ++j) acc[i][j] = 0.0f;

        const float* bblk = cb + (size_t)kt * DIMD;
        for (int dc = 0; dc < DIMD; dc += DK) {
            __syncthreads();
            #pragma unroll
            for (int p = 0; p < 4; ++p) {
                const int r = p * 32 + sr;
                float4 va = *(const float4*)(xblk + (size_t)r * DIMD + dc + sd);
                float4 vb = *(const float4*)(bblk + (size_t)r * DIMD + dc + sd);
                As[(sd + 0) * LSTR + r] = va.x;
                As[(sd + 1) * LSTR + r] = va.y;
                As[(sd + 2) * LSTR + r] = va.z;
                As[(sd + 3) * LSTR + r] = va.w;
                Bs[(sd + 0) * LSTR + r] = vb.x;
                Bs[(sd + 1) * LSTR + r] = vb.y;
                Bs[(sd + 2) * LSTR + r] = vb.z;
                Bs[(sd + 3) * LSTR + r] = vb.w;
            }
            __syncthreads();
            #pragma unroll 4
            for (int d = 0; d < DK; ++d) {
                const float2* ap = (const float2*)&As[d * LSTR + ty * 8];
                const float2* bp = (const float2*)&Bs[d * LSTR + tx * 8];
                float2 a0 = ap[0], a1 = ap[1], a2 = ap[2], a3 = ap[3];
                float2 c0 = bp[0], c1 = bp[1], c2 = bp[2], c3 = bp[3];
                float a[8] = {a0.x, a0.y, a1.x, a1.y, a2.x, a2.y, a3.x, a3.y};
                float b[8] = {c0.x, c0.y, c1.x, c1.y, c2.x, c2.y, c3.x, c3.y};
                #pragma unroll
                for (int i = 0; i < 8; ++i)
                    #pragma unroll
                    for (int j = 0; j < 8; ++j)
                        acc[i][j] += a[i] * b[j];
            }
        }
        // Screen metric: -2*dot (e_sq is absorbed in the np reference; z_sq is a
        // row constant). Ascending code order + strict '<' = first-min semantics.
        #pragma unroll
        for (int j = 0; j < 8; ++j) {
            const int code = kt + tx * 8 + j;
            #pragma unroll
            for (int i = 0; i < 8; ++i) {
                const float dist = -(acc[i][j] + acc[i][j]);
                if (dist < b1[i]) { b2[i] = b1[i]; b1[i] = dist; i1[i] = code; }
                else if (dist < b2[i]) b2[i] = dist;
            }
        }
    }

    __syncthreads();
    #pragma unroll
    for (int i = 0; i < 8; ++i) {
        red_d[(ty * 8 + i) * 17 + tx] = b1[i];
        red_2[(ty * 8 + i) * 17 + tx] = b2[i];
        red_i[(ty * 8 + i) * 17 + tx] = i1[i];
    }
    __syncthreads();
    if (tid < MT) {
        float bd = red_d[tid * 17];
        float s2 = red_2[tid * 17];
        int   bi = red_i[tid * 17];
        #pragma unroll
        for (int t = 1; t < 16; ++t) {
            const float d1 = red_d[tid * 17 + t];
            const float d2 = red_2[tid * 17 + t];
            const int   ii = red_i[tid * 17 + t];
            if (d1 < bd || (d1 == bd && ii < bi)) {
                s2 = fminf(bd, d2);
                bd = d1; bi = ii;
            } else {
                s2 = fminf(s2, d1);
            }
        }
        const int row = blockIdx.x * MT + tid;
        widx[tid] = bi;
        out[OUT_IDX + (size_t)row] = (float)bi;
        // gap within one fp32 bin of the np metric -> quantized tie possible
        if (s2 - bd <= FLAG_EPS) {
            const int pos = atomicAdd(wcount, 1);
            if (pos < wcap) wlist[pos] = row;
        }
    }
    __syncthreads();

    // Gather z_q, write z_q_st = x + (z_q - x), accumulate loss partial.
    float lsum = 0.0f;
    const int dv = (tid & 63) * 4;
    const int rs = tid >> 6;
    float* oblk = out + (size_t)blockIdx.x * MT * DIMD;
    for (int p = 0; p < 32; ++p) {
        const int row = p * 4 + rs;
        const int w = widx[row];
        float4 xv = *(const float4*)(xblk + (size_t)row * DIMD + dv);
        float4 cv = *(const float4*)(cb + (size_t)w * DIMD + dv);
        const float d0 = cv.x - xv.x, d1 = cv.y - xv.y, d2 = cv.z - xv.z, d3 = cv.w - xv.w;
        float4 o;
        o.x = xv.x + d0; o.y = xv.y + d1; o.z = xv.z + d2; o.w = xv.w + d3;
        *(float4*)(oblk + (size_t)row * DIMD + dv) = o;
        lsum += d0 * d0 + d1 * d1 + d2 * d2 + d3 * d3;
    }
    #pragma unroll
    for (int off = 32; off > 0; off >>= 1) lsum += __shfl_down(lsum, off, 64);
    if ((tid & 63) == 0) wpart[tid >> 6] = lsum;
    __syncthreads();
    if (tid == 0) atomicAdd(loss_acc, wpart[0] + wpart[1] + wpart[2] + wpart[3]);
}

// Rescan flagged rows with the np-emulated quantized metric:
//   dq_k = fl32( z_sq_f32 - fl32(2 * dot_fp64) ),  argmin first-index.
// z_sq need only be grid-aligned (fp32 in the right binade): fl(Z - w) is
// translation-invariant in Z by ulp multiples, so fp64-sum->fp32 matches np's
// pairwise-fp32 z_sq tie structure.
__global__ __launch_bounds__(256) void vq_fix_kernel(const float* __restrict__ x,
                                                     const float* __restrict__ cb,
                                                     float* __restrict__ out,
                                                     float* __restrict__ loss_acc,
                                                     const int* __restrict__ wcount,
                                                     const int* __restrict__ wlist,
                                                     int wcap) {
    __shared__ double xd[DIMD];
    __shared__ double zred[256];
    __shared__ float  rdq[256];
    __shared__ int    ri[256];
    __shared__ float  lred[256];
    const int tid = threadIdx.x;
    int count = wcount[0];
    if (count > wcap) count = wcap;
    for (int item = blockIdx.x; item < count; item += gridDim.x) {
        const int row = wlist[item];
        const double xv0 = (double)x[(size_t)row * DIMD + tid];
        xd[tid] = xv0;
        zred[tid] = xv0 * xv0;
        __syncthreads();
        for (int st = 128; st > 0; st >>= 1) {
            if (tid < st) zred[tid] += zred[tid + st];
            __syncthreads();
        }
        const float Zf = (float)zred[0];     // grid-aligned z_sq
        float bq = 3.4e38f; int bi = 0;
        for (int c = tid; c < KCODES; c += 256) {      // ascending per thread
            const float* cr = cb + (size_t)c * DIMD;
            double s = 0.0;
            for (int d = 0; d < DIMD; d += 4) {
                float4 cv = *(const float4*)(cr + d);
                s += xd[d + 0] * (double)cv.x + xd[d + 1] * (double)cv.y
                   + xd[d + 2] * (double)cv.z + xd[d + 3] * (double)cv.w;
            }
            const float w = (float)(2.0 * s); // np's fp32 dot (x2 exact)
            const float dq = Zf - w;          // fp32 subtract = np's quantization
            if (dq < bq) { bq = dq; bi = c; } // strict < keeps first index
        }
        rdq[tid] = bq; ri[tid] = bi;
        __syncthreads();
        for (int st = 128; st > 0; st >>= 1) {
            if (tid < st) {
                const float oq = rdq[tid + st]; const int oi = ri[tid + st];
                if (oq < rdq[tid] || (oq == rdq[tid] && oi < ri[tid])) {
                    rdq[tid] = oq; ri[tid] = oi;
                }
            }
            __syncthreads();
        }
        const int newi = ri[0];
        const int oldi = (int)out[OUT_IDX + (size_t)row];
        if (newi != oldi) {
            const float xv = x[(size_t)row * DIMD + tid];
            const float co = cb[(size_t)oldi * DIMD + tid];
            const float cn = cb[(size_t)newi * DIMD + tid];
            const float dold = co - xv, dnew = cn - xv;
            out[(size_t)row * DIMD + tid] = xv + dnew;
            lred[tid] = dnew * dnew - dold * dold;
        } else {
            lred[tid] = 0.0f;
        }
        __syncthreads();
        for (int st = 128; st > 0; st >>= 1) {
            if (tid < st) lred[tid] += lred[tid + st];
            __syncthreads();
        }
        if (tid == 0 && newi != oldi) {
            atomicAdd(loss_acc, lred[0]);
            out[OUT_IDX + (size_t)row] = (float)newi;
        }
        __syncthreads();   // protect xd before next item overwrites
    }
}

__global__ void finalize_kernel(const float* __restrict__ loss_acc, float* __restrict__ out) {
    if (threadIdx.x == 0 && blockIdx.x == 0)
        out[OUT_LOSS] = 1.25f * (loss_acc[0] / 8388608.0f);
}

extern "C" void kernel_launch(void* const* d_in, const int* in_sizes, int n_in,
                              void* d_out, int out_size, void* d_ws, size_t ws_size,
                              hipStream_t stream) {
    const float* x  = (const float*)d_in[0];
    const float* cb = (const float*)d_in[1];
    float* out = (float*)d_out;
    float* loss_acc = (float*)d_ws;
    int*   wcount   = (int*)((char*)d_ws + 32);
    int*   wlist    = (int*)((char*)d_ws + 4096);
    int wcap = 0;
    if (ws_size > 4096 + sizeof(int)) {
        size_t c = (ws_size - 4096) / sizeof(int);
        wcap = (int)(c > 32768 ? 32768 : c);
    }

    init_kernel<<<1, 64, 0, stream>>>(loss_acc, wcount);
    vq_main_kernel<<<256, 256, 0, stream>>>(x, cb, out, loss_acc, wcount, wlist, wcap);
    vq_fix_kernel<<<512, 256, 0, stream>>>(x, cb, out, loss_acc, wcount, wlist, wcap);
    finalize_kernel<<<1, 1, 0, stream>>>(loss_acc, out);
}

// Round 4
// 780.674 us; speedup vs baseline: 2.1936x; 2.1936x over previous
//
#include <hip/hip_runtime.h>

// VectorQuantizer: x [8,16,256,256] fp32 -> N=32768 rows, D=256; codebook K=4096 x 256.
// d_out flat (read back as float32):
//   [0 .. 8388608)   z_q_st  (= codebook[argmin])
//   [8388608]        loss = 1.25 * mean((z_q - x)^2)
//   [8388609 ..)     encoding indices, written as float values
//
// R3 (passed, absmax 0): fp32 GEMM screen on -2*dot, flag rows with top-2 gap
// <= 3.6e-5, fp64 fix pass emulating np's quantized metric fl32(Zf - fl32(2*dot)).
// R4: screen engine -> split-bf16 MFMA (z*e ~ zh*eh + zh*el + zl*eh, err ~3e-8,
// << 5.5e-6 flag margin => flagged set unchanged in effect; unflagged rows have
// gap > 3.6e-5 >> err). Fix kernel kept BIT-IDENTICAL to R3.
typedef __attribute__((ext_vector_type(8))) short bf16x8;
typedef __attribute__((ext_vector_type(4))) float f32x4;

#define DIMD 256
#define KCODES 4096
#define NROWS 32768
#define OUT_LOSS 8388608
#define OUT_IDX  8388609
#define FLAG_EPS 3.6e-5f

// ws layout (bytes): loss f32 @0 | wcount i32 @32 | wlist i32[32768] @4096 |
// bf16 planes @1MB: A_hi, A_lo (16.78 MB each), B_hi, B_lo (2.1 MB each)
#define WS_AHI  (1024u*1024u)
#define WS_ALO  (WS_AHI + (unsigned)NROWS*DIMD*2u)
#define WS_BHI  (WS_ALO + (unsigned)NROWS*DIMD*2u)
#define WS_BLO  (WS_BHI + (unsigned)KCODES*DIMD*2u)
#define WS_END  (WS_BLO + (unsigned)KCODES*DIMD*2u)   // 38,797,312

__device__ __forceinline__ unsigned short bf16_rne(float f) {
    unsigned u = __float_as_uint(f);
    u += 0x7FFFu + ((u >> 16) & 1u);
    return (unsigned short)(u >> 16);
}
__device__ __forceinline__ float bf16_f(unsigned short h) {
    return __uint_as_float(((unsigned)h) << 16);
}

__global__ void init_kernel(float* __restrict__ loss_acc, int* __restrict__ wcount) {
    if (threadIdx.x == 0) { loss_acc[0] = 0.0f; wcount[0] = 0; }
}

// Split fp32 -> bf16 hi + bf16 lo planes (any faithful split works; only |residual|
// ~2^-17 matters for the screen error budget).
__global__ __launch_bounds__(256) void convert_kernel(const float* __restrict__ src,
                                                      unsigned short* __restrict__ hi,
                                                      unsigned short* __restrict__ lo) {
    const size_t e = ((size_t)blockIdx.x * 256 + threadIdx.x) * 4;
    float4 v = *(const float4*)(src + e);
    ushort4 h, l;
    h.x = bf16_rne(v.x); l.x = bf16_rne(v.x - bf16_f(h.x));
    h.y = bf16_rne(v.y); l.y = bf16_rne(v.y - bf16_f(h.y));
    h.z = bf16_rne(v.z); l.z = bf16_rne(v.z - bf16_f(h.z));
    h.w = bf16_rne(v.w); l.w = bf16_rne(v.w - bf16_f(h.w));
    *(ushort4*)(hi + e) = h;
    *(ushort4*)(lo + e) = l;
}

// MFMA screen: 512 blocks x 64 rows. Wave grid 2x2 over the 64x128 (rows x codes)
// tile; wave tile 32 rows x 64 codes = 2x4 frags of 16x16. A frags (2 rf x 8 kc x
// hi/lo) persistent in registers (128 VGPR); B staged in LDS (BK=64, stride 72 bf16
// -> 16B-aligned rows, uniform bank spread). 3 MFMA passes per kstep: hh, hl, lh.
__global__ __launch_bounds__(256, 2) void vq_screen_kernel(
        const unsigned short* __restrict__ Ahi, const unsigned short* __restrict__ Alo,
        const unsigned short* __restrict__ Bhi, const unsigned short* __restrict__ Blo,
        const float* __restrict__ x, const float* __restrict__ cb,
        float* __restrict__ out, float* __restrict__ loss_acc,
        int* __restrict__ wcount, int* __restrict__ wlist, int wcap) {
    __shared__ short BsH[128 * 72];
    __shared__ short BsL[128 * 72];
    __shared__ float red1[64 * 33];
    __shared__ float red2[64 * 33];
    __shared__ int   redi[64 * 33];
    __shared__ int   widx[64];
    __shared__ float wpart[4];

    const int tid   = threadIdx.x;
    const int w     = tid >> 6;
    const int lane  = tid & 63;
    const int lanem = lane & 15;
    const int laneq = lane >> 4;
    const int rbase = (w & 1) * 32;      // wave row base within block tile
    const int cb0   = (w >> 1) * 64;     // wave col base within code tile
    const int rb    = blockIdx.x * 64;   // global row base

    // Persistent A fragments: ah/al[rowfrag][kchunk16]
    bf16x8 ah[2][8], al[2][8];
    #pragma unroll
    for (int i = 0; i < 2; ++i) {
        const size_t grow = (size_t)(rb + rbase + i * 16 + lanem) * DIMD;
        #pragma unroll
        for (int kc = 0; kc < 8; ++kc) {
            ah[i][kc] = *(const bf16x8*)(Ahi + grow + kc * 32 + laneq * 8);
            al[i][kc] = *(const bf16x8*)(Alo + grow + kc * 32 + laneq * 8);
        }
    }

    float b1[8], b2[8];
    int   i1[8];
    #pragma unroll
    for (int s = 0; s < 8; ++s) { b1[s] = 3.4e38f; b2[s] = 3.4e38f; i1[s] = 0; }

    const int srow = tid >> 1;           // staging: 2 threads/code-row
    const int sh   = tid & 1;            // k-half (32 bf16 each)

    for (int ct = 0; ct < KCODES / 128; ++ct) {
        const int ctb = ct * 128;
        f32x4 acc[2][4];
        #pragma unroll
        for (int i = 0; i < 2; ++i)
            #pragma unroll
            for (int j = 0; j < 4; ++j)
                acc[i][j] = (f32x4){0.f, 0.f, 0.f, 0.f};

        #pragma unroll
        for (int c = 0; c < 4; ++c) {    // BK=64 chunks
            __syncthreads();
            {
                const size_t gbase = (size_t)(ctb + srow) * DIMD + c * 64 + sh * 32;
                const int lbase = srow * 72 + sh * 32;
                #pragma unroll
                for (int u = 0; u < 4; ++u) {
                    *(bf16x8*)&BsH[lbase + u * 8] = *(const bf16x8*)(Bhi + gbase + u * 8);
                    *(bf16x8*)&BsL[lbase + u * 8] = *(const bf16x8*)(Blo + gbase + u * 8);
                }
            }
            __syncthreads();
            #pragma unroll
            for (int s = 0; s < 2; ++s) {    // two K=32 MFMA steps per chunk
                const int kc = c * 2 + s;
                bf16x8 bh[4], bl[4];
                #pragma unroll
                for (int j = 0; j < 4; ++j) {
                    const int br = (cb0 + j * 16 + lanem) * 72 + s * 32 + laneq * 8;
                    bh[j] = *(const bf16x8*)&BsH[br];
                    bl[j] = *(const bf16x8*)&BsL[br];
                }
                #pragma unroll
                for (int i = 0; i < 2; ++i)
                    #pragma unroll
                    for (int j = 0; j < 4; ++j) {
                        acc[i][j] = __builtin_amdgcn_mfma_f32_16x16x32_bf16(ah[i][kc], bh[j], acc[i][j], 0, 0, 0);
                        acc[i][j] = __builtin_amdgcn_mfma_f32_16x16x32_bf16(ah[i][kc], bl[j], acc[i][j], 0, 0, 0);
                        acc[i][j] = __builtin_amdgcn_mfma_f32_16x16x32_bf16(al[i][kc], bh[j], acc[i][j], 0, 0, 0);
                    }
            }
        }
        // Screen metric: -2*dot. C layout (m89-verified): col=lane&15, row=quad*4+reg.
        // Codes ascend within lane (j, then ct) -> strict '<' keeps first-min in-lane.
        #pragma unroll
        for (int i = 0; i < 2; ++i)
            #pragma unroll
            for (int r = 0; r < 4; ++r) {
                const int s = i * 4 + r;
                #pragma unroll
                for (int j = 0; j < 4; ++j) {
                    const float v = acc[i][j][r];
                    const float dist = -(v + v);
                    if (dist < b1[s]) { b2[s] = b1[s]; b1[s] = dist; i1[s] = ctb + cb0 + j * 16 + lanem; }
                    else if (dist < b2[s]) b2[s] = dist;
                }
            }
    }

    __syncthreads();
    #pragma unroll
    for (int i = 0; i < 2; ++i)
        #pragma unroll
        for (int r = 0; r < 4; ++r) {
            const int s = i * 4 + r;
            const int rr = rbase + i * 16 + laneq * 4 + r;   // row within block
            const int src = (w >> 1) * 16 + lanem;           // source column 0..31
            red1[rr * 33 + src] = b1[s];
            red2[rr * 33 + src] = b2[s];
            redi[rr * 33 + src] = i1[s];
        }
    __syncthreads();
    if (tid < 64) {
        float bd = red1[tid * 33];
        float s2 = red2[tid * 33];
        int   bi = redi[tid * 33];
        for (int t = 1; t < 32; ++t) {
            const float d1 = red1[tid * 33 + t];
            const float d2 = red2[tid * 33 + t];
            const int   ii = redi[tid * 33 + t];
            if (d1 < bd || (d1 == bd && ii < bi)) { s2 = fminf(bd, d2); bd = d1; bi = ii; }
            else s2 = fminf(s2, d1);
        }
        const int row = rb + tid;
        widx[tid] = bi;
        out[OUT_IDX + (size_t)row] = (float)bi;
        if (s2 - bd <= FLAG_EPS) {
            const int pos = atomicAdd(wcount, 1);
            if (pos < wcap) wlist[pos] = row;
        }
    }
    __syncthreads();

    // Gather z_q, write z_q_st = x + (z_q - x), accumulate loss partial.
    float lsum = 0.0f;
    const int dv = (tid & 63) * 4;
    const int rs = tid >> 6;
    const float* xblk = x + (size_t)rb * DIMD;
    float* oblk = out + (size_t)rb * DIMD;
    for (int p = 0; p < 16; ++p) {
        const int row = p * 4 + rs;
        const int wi = widx[row];
        float4 xv = *(const float4*)(xblk + (size_t)row * DIMD + dv);
        float4 cv = *(const float4*)(cb + (size_t)wi * DIMD + dv);
        const float d0 = cv.x - xv.x, d1 = cv.y - xv.y, d2 = cv.z - xv.z, d3 = cv.w - xv.w;
        float4 o;
        o.x = xv.x + d0; o.y = xv.y + d1; o.z = xv.z + d2; o.w = xv.w + d3;
        *(float4*)(oblk + (size_t)row * DIMD + dv) = o;
        lsum += d0 * d0 + d1 * d1 + d2 * d2 + d3 * d3;
    }
    #pragma unroll
    for (int off = 32; off > 0; off >>= 1) lsum += __shfl_down(lsum, off, 64);
    if ((tid & 63) == 0) wpart[tid >> 6] = lsum;
    __syncthreads();
    if (tid == 0) atomicAdd(loss_acc, wpart[0] + wpart[1] + wpart[2] + wpart[3]);
}

// ===== fix kernel: BIT-IDENTICAL to R3 (np-bin emulation, fp64) =====
__global__ __launch_bounds__(256) void vq_fix_kernel(const float* __restrict__ x,
                                                     const float* __restrict__ cb,
                                                     float* __restrict__ out,
                                                     float* __restrict__ loss_acc,
                                                     const int* __restrict__ wcount,
                                                     const int* __restrict__ wlist,
                                                     int wcap) {
    __shared__ double xd[DIMD];
    __shared__ double zred[256];
    __shared__ float  rdq[256];
    __shared__ int    ri[256];
    __shared__ float  lred[256];
    const int tid = threadIdx.x;
    int count = wcount[0];
    if (count > wcap) count = wcap;
    for (int item = blockIdx.x; item < count; item += gridDim.x) {
        const int row = wlist[item];
        const double xv0 = (double)x[(size_t)row * DIMD + tid];
        xd[tid] = xv0;
        zred[tid] = xv0 * xv0;
        __syncthreads();
        for (int st = 128; st > 0; st >>= 1) {
            if (tid < st) zred[tid] += zred[tid + st];
            __syncthreads();
        }
        const float Zf = (float)zred[0];
        float bq = 3.4e38f; int bi = 0;
        for (int c = tid; c < KCODES; c += 256) {
            const float* cr = cb + (size_t)c * DIMD;
            double s = 0.0;
            for (int d = 0; d < DIMD; d += 4) {
                float4 cv = *(const float4*)(cr + d);
                s += xd[d + 0] * (double)cv.x + xd[d + 1] * (double)cv.y
                   + xd[d + 2] * (double)cv.z + xd[d + 3] * (double)cv.w;
            }
            const float w = (float)(2.0 * s);
            const float dq = Zf - w;
            if (dq < bq) { bq = dq; bi = c; }
        }
        rdq[tid] = bq; ri[tid] = bi;
        __syncthreads();
        for (int st = 128; st > 0; st >>= 1) {
            if (tid < st) {
                const float oq = rdq[tid + st]; const int oi = ri[tid + st];
                if (oq < rdq[tid] || (oq == rdq[tid] && oi < ri[tid])) {
                    rdq[tid] = oq; ri[tid] = oi;
                }
            }
            __syncthreads();
        }
        const int newi = ri[0];
        const int oldi = (int)out[OUT_IDX + (size_t)row];
        if (newi != oldi) {
            const float xv = x[(size_t)row * DIMD + tid];
            const float co = cb[(size_t)oldi * DIMD + tid];
            const float cn = cb[(size_t)newi * DIMD + tid];
            const float dold = co - xv, dnew = cn - xv;
            out[(size_t)row * DIMD + tid] = xv + dnew;
            lred[tid] = dnew * dnew - dold * dold;
        } else {
            lred[tid] = 0.0f;
        }
        __syncthreads();
        for (int st = 128; st > 0; st >>= 1) {
            if (tid < st) lred[tid] += lred[tid + st];
            __syncthreads();
        }
        if (tid == 0 && newi != oldi) {
            atomicAdd(loss_acc, lred[0]);
            out[OUT_IDX + (size_t)row] = (float)newi;
        }
        __syncthreads();
    }
}

__global__ void finalize_kernel(const float* __restrict__ loss_acc, float* __restrict__ out) {
    if (threadIdx.x == 0 && blockIdx.x == 0)
        out[OUT_LOSS] = 1.25f * (loss_acc[0] / 8388608.0f);
}

// ===== fallback fp32 screen (R3, proven) for small ws_size =====
#define MT 128
#define DK 32
#define LSTR 130
__global__ __launch_bounds__(256) void vq_main_fp32_kernel(const float* __restrict__ x,
                                                           const float* __restrict__ cb,
                                                           float* __restrict__ out,
                                                           float* __restrict__ loss_acc,
                                                           int* __restrict__ wcount,
                                                           int* __restrict__ wlist,
                                                           int wcap) {
    __shared__ float As[DK * LSTR];
    __shared__ float Bs[DK * LSTR];
    __shared__ float red_d[MT * 17];
    __shared__ float red_2[MT * 17];
    __shared__ int   red_i[MT * 17];
    __shared__ int   widx[MT];
    __shared__ float wpart[4];
    const int tid = threadIdx.x;
    const int tx = tid & 15;
    const int ty = tid >> 4;
    const float* xblk = x + (size_t)blockIdx.x * MT * DIMD;
    float b1[8], b2[8]; int i1[8];
    #pragma unroll
    for (int i = 0; i < 8; ++i) { b1[i] = 3.4e38f; b2[i] = 3.4e38f; i1[i] = 0; }
    const int sr = tid >> 3;
    const int sd = (tid & 7) * 4;
    for (int kt = 0; kt < KCODES; kt += 128) {
        float acc[8][8];
        #pragma unroll
        for (int i = 0; i < 8; ++i)
            #pragma unroll
            for (int j = 0; j < 8; ++j) acc[i][j] = 0.0f;
        const float* bblk = cb + (size_t)kt * DIMD;
        for (int dc = 0; dc < DIMD; dc += DK) {
            __syncthreads();
            #pragma unroll
            for (int p = 0; p < 4; ++p) {
                const int r = p * 32 + sr;
                float4 va = *(const float4*)(xblk + (size_t)r * DIMD + dc + sd);
                float4 vb = *(const float4*)(bblk + (size_t)r * DIMD + dc + sd);
                As[(sd + 0) * LSTR + r] = va.x; As[(sd + 1) * LSTR + r] = va.y;
                As[(sd + 2) * LSTR + r] = va.z; As[(sd + 3) * LSTR + r] = va.w;
                Bs[(sd + 0) * LSTR + r] = vb.x; Bs[(sd + 1) * LSTR + r] = vb.y;
                Bs[(sd + 2) * LSTR + r] = vb.z; Bs[(sd + 3) * LSTR + r] = vb.w;
            }
            __syncthreads();
            #pragma unroll 4
            for (int d = 0; d < DK; ++d) {
                const float2* ap = (const float2*)&As[d * LSTR + ty * 8];
                const float2* bp = (const float2*)&Bs[d * LSTR + tx * 8];
                float2 a0 = ap[0], a1 = ap[1], a2 = ap[2], a3 = ap[3];
                float2 c0 = bp[0], c1 = bp[1], c2 = bp[2], c3 = bp[3];
                float a[8] = {a0.x, a0.y, a1.x, a1.y, a2.x, a2.y, a3.x, a3.y};
                float b[8] = {c0.x, c0.y, c1.x, c1.y, c2.x, c2.y, c3.x, c3.y};
                #pragma unroll
                for (int i = 0; i < 8; ++i)
                    #pragma unroll
                    for (int j = 0; j < 8; ++j)
                        acc[i][j] += a[i] * b[j];
            }
        }
        #pragma unroll
        for (int j = 0; j < 8; ++j) {
            const int code = kt + tx * 8 + j;
            #pragma unroll
            for (int i = 0; i < 8; ++i) {
                const float dist = -(acc[i][j] + acc[i][j]);
                if (dist < b1[i]) { b2[i] = b1[i]; b1[i] = dist; i1[i] = code; }
                else if (dist < b2[i]) b2[i] = dist;
            }
        }
    }
    __syncthreads();
    #pragma unroll
    for (int i = 0; i < 8; ++i) {
        red_d[(ty * 8 + i) * 17 + tx] = b1[i];
        red_2[(ty * 8 + i) * 17 + tx] = b2[i];
        red_i[(ty * 8 + i) * 17 + tx] = i1[i];
    }
    __syncthreads();
    if (tid < MT) {
        float bd = red_d[tid * 17];
        float s2 = red_2[tid * 17];
        int   bi = red_i[tid * 17];
        #pragma unroll
        for (int t = 1; t < 16; ++t) {
            const float d1 = red_d[tid * 17 + t];
            const float d2 = red_2[tid * 17 + t];
            const int   ii = red_i[tid * 17 + t];
            if (d1 < bd || (d1 == bd && ii < bi)) { s2 = fminf(bd, d2); bd = d1; bi = ii; }
            else s2 = fminf(s2, d1);
        }
        const int row = blockIdx.x * MT + tid;
        widx[tid] = bi;
        out[OUT_IDX + (size_t)row] = (float)bi;
        if (s2 - bd <= FLAG_EPS) {
            const int pos = atomicAdd(wcount, 1);
            if (pos < wcap) wlist[pos] = row;
        }
    }
    __syncthreads();
    float lsum = 0.0f;
    const int dv = (tid & 63) * 4;
    const int rs = tid >> 6;
    float* oblk = out + (size_t)blockIdx.x * MT * DIMD;
    for (int p = 0; p < 32; ++p) {
        const int row = p * 4 + rs;
        const int wi = widx[row];
        float4 xv = *(const float4*)(xblk + (size_t)row * DIMD + dv);
        float4 cv = *(const float4*)(cb + (size_t)wi * DIMD + dv);
        const float d0 = cv.x - xv.x, d1 = cv.y - xv.y, d2 = cv.z - xv.z, d3 = cv.w - xv.w;
        float4 o;
        o.x = xv.x + d0; o.y = xv.y + d1; o.z = xv.z + d2; o.w = xv.w + d3;
        *(float4*)(oblk + (size_t)row * DIMD + dv) = o;
        lsum += d0 * d0 + d1 * d1 + d2 * d2 + d3 * d3;
    }
    #pragma unroll
    for (int off = 32; off > 0; off >>= 1) lsum += __shfl_down(lsum, off, 64);
    if ((tid & 63) == 0) wpart[tid >> 6] = lsum;
    __syncthreads();
    if (tid == 0) atomicAdd(loss_acc, wpart[0] + wpart[1] + wpart[2] + wpart[3]);
}

extern "C" void kernel_launch(void* const* d_in, const int* in_sizes, int n_in,
                              void* d_out, int out_size, void* d_ws, size_t ws_size,
                              hipStream_t stream) {
    const float* x  = (const float*)d_in[0];
    const float* cb = (const float*)d_in[1];
    float* out = (float*)d_out;
    float* loss_acc = (float*)d_ws;
    int*   wcount   = (int*)((char*)d_ws + 32);
    int*   wlist    = (int*)((char*)d_ws + 4096);
    int wcap = 0;
    if (ws_size > 4096 + sizeof(int)) {
        size_t c = (ws_size - 4096) / sizeof(int);
        wcap = (int)(c > 32768 ? 32768 : c);
    }

    init_kernel<<<1, 64, 0, stream>>>(loss_acc, wcount);
    if (ws_size >= (size_t)WS_END) {
        unsigned short* Ahi = (unsigned short*)((char*)d_ws + WS_AHI);
        unsigned short* Alo = (unsigned short*)((char*)d_ws + WS_ALO);
        unsigned short* Bhi = (unsigned short*)((char*)d_ws + WS_BHI);
        unsigned short* Blo = (unsigned short*)((char*)d_ws + WS_BLO);
        convert_kernel<<<8192, 256, 0, stream>>>(x, Ahi, Alo);
        convert_kernel<<<1024, 256, 0, stream>>>(cb, Bhi, Blo);
        vq_screen_kernel<<<512, 256, 0, stream>>>(Ahi, Alo, Bhi, Blo, x, cb, out,
                                                  loss_acc, wcount, wlist, wcap);
    } else {
        vq_main_fp32_kernel<<<256, 256, 0, stream>>>(x, cb, out, loss_acc,
                                                     wcount, wlist, wcap);
    }
    vq_fix_kernel<<<512, 256, 0, stream>>>(x, cb, out, loss_acc, wcount, wlist, wcap);
    finalize_kernel<<<1, 1, 0, stream>>>(loss_acc, out);
}

// Round 5
// 626.172 us; speedup vs baseline: 2.7348x; 1.2467x over previous
//
#include <hip/hip_runtime.h>

// VectorQuantizer: x [8,16,256,256] fp32 -> N=32768 rows, D=256; codebook K=4096 x 256.
// d_out flat (read back as float32):
//   [0 .. 8388608)   z_q_st  (= codebook[argmin])
//   [8388608]        loss = 1.25 * mean((z_q - x)^2)
//   [8388609 ..)     encoding indices, written as float values
//
// Pipeline (R5):
//   convert: fp32 -> bf16 hi/lo planes (Markstein split; residual ~1e-7 worst case)
//   screen:  split-bf16 MFMA GEMM on -2*dot (3 terms: hh+hl+lh), per-lane TOP-3,
//            cross-lane reduce -> row min + ALL candidates within FLAG_EPS.
//            1 candidate -> done. 2..8 -> candidate list. >8 -> overflow list.
//   candfix: one wave per flagged row, exact np-bin metric fl32(Zf - fl32(2*dot64))
//            over the <=8 candidates only, (dq, idx)-lexicographic first-min.
//   overflow: old full-scan fp64 kernel (expected 0 items; pure safety net).
// Monotonicity of fp32 rounding => only codes within ulp(z_sq) (<=3.05e-5) of the
// true row min can share np's winning bin; FLAG_EPS=3.6e-5 covers ulp + 2*screen_err.
typedef __attribute__((ext_vector_type(8))) short bf16x8;
typedef __attribute__((ext_vector_type(4))) float f32x4;

#define DIMD 256
#define KCODES 4096
#define NROWS 32768
#define OUT_LOSS 8388608
#define OUT_IDX  8388609
#define FLAG_EPS 3.6e-5f
#define MAXC 8

struct CandEntry { int row; int cnt; int codes[MAXC]; };   // 40 B

// ws layout (bytes): loss f32 @0 | wcount i32 @32 | ovfcount i32 @36 |
// clist @4096 (8192 entries x 40 B) | ovflist @393216 (4096 i32) |
// bf16 planes @1MB: A_hi, A_lo (16.78 MB each), B_hi, B_lo (2.1 MB each)
#define WS_CLIST 4096u
#define CCAP     8192
#define WS_OVF   393216u
#define OVFCAP   4096
#define WS_AHI  (1024u*1024u)
#define WS_ALO  (WS_AHI + (unsigned)NROWS*DIMD*2u)
#define WS_BHI  (WS_ALO + (unsigned)NROWS*DIMD*2u)
#define WS_BLO  (WS_BHI + (unsigned)KCODES*DIMD*2u)
#define WS_END  (WS_BLO + (unsigned)KCODES*DIMD*2u)   // 38,797,312

__device__ __forceinline__ unsigned short bf16_rne(float f) {
    unsigned u = __float_as_uint(f);
    u += 0x7FFFu + ((u >> 16) & 1u);
    return (unsigned short)(u >> 16);
}
__device__ __forceinline__ float bf16_f(unsigned short h) {
    return __uint_as_float(((unsigned)h) << 16);
}

__global__ void init_kernel(float* __restrict__ loss_acc, int* __restrict__ wcount,
                            int* __restrict__ ovfcount) {
    if (threadIdx.x == 0) { loss_acc[0] = 0.0f; wcount[0] = 0; ovfcount[0] = 0; }
}

__global__ __launch_bounds__(256) void convert_kernel(const float* __restrict__ src,
                                                      unsigned short* __restrict__ hi,
                                                      unsigned short* __restrict__ lo) {
    const size_t e = ((size_t)blockIdx.x * 256 + threadIdx.x) * 4;
    float4 v = *(const float4*)(src + e);
    ushort4 h, l;
    h.x = bf16_rne(v.x); l.x = bf16_rne(v.x - bf16_f(h.x));
    h.y = bf16_rne(v.y); l.y = bf16_rne(v.y - bf16_f(h.y));
    h.z = bf16_rne(v.z); l.z = bf16_rne(v.z - bf16_f(h.z));
    h.w = bf16_rne(v.w); l.w = bf16_rne(v.w - bf16_f(h.w));
    *(ushort4*)(hi + e) = h;
    *(ushort4*)(lo + e) = l;
}

// LDS union: B staging (K loop) then reduction arrays (after K loop). 49,664 B.
struct ScreenLdsStage { short BsH[128 * 72]; short BsL[128 * 72]; };
struct ScreenLdsRed   { float val[64 * 97]; int idx[64 * 97]; };  // [row][src*3+slot]
union ScreenLds { ScreenLdsStage s; ScreenLdsRed r; };

__global__ __launch_bounds__(256, 2) void vq_screen_kernel(
        const unsigned short* __restrict__ Ahi, const unsigned short* __restrict__ Alo,
        const unsigned short* __restrict__ Bhi, const unsigned short* __restrict__ Blo,
        const float* __restrict__ x, const float* __restrict__ cb,
        float* __restrict__ out, float* __restrict__ loss_acc,
        int* __restrict__ wcount, CandEntry* __restrict__ clist,
        int* __restrict__ ovfcount, int* __restrict__ ovflist) {
    __shared__ ScreenLds u;
    __shared__ int   widx[64];
    __shared__ float wpart[4];

    const int tid   = threadIdx.x;
    const int w     = tid >> 6;
    const int lane  = tid & 63;
    const int lanem = lane & 15;
    const int laneq = lane >> 4;
    const int rbase = (w & 1) * 32;
    const int cb0   = (w >> 1) * 64;
    const int rb    = blockIdx.x * 64;

    // Persistent A fragments (128 VGPR)
    bf16x8 ah[2][8], al[2][8];
    #pragma unroll
    for (int i = 0; i < 2; ++i) {
        const size_t grow = (size_t)(rb + rbase + i * 16 + lanem) * DIMD;
        #pragma unroll
        for (int kc = 0; kc < 8; ++kc) {
            ah[i][kc] = *(const bf16x8*)(Ahi + grow + kc * 32 + laneq * 8);
            al[i][kc] = *(const bf16x8*)(Alo + grow + kc * 32 + laneq * 8);
        }
    }

    // Per-lane TOP-3 (candidate completeness: a global candidate is lost only if
    // >=4 candidates land in one lane's 128-code subset — P ~ 7e-4 dataset-wide).
    float b1[8], b2[8], b3[8];
    int   i1[8], i2[8], i3[8];
    #pragma unroll
    for (int s = 0; s < 8; ++s) {
        b1[s] = 3.4e38f; b2[s] = 3.4e38f; b3[s] = 3.4e38f;
        i1[s] = 0; i2[s] = 0; i3[s] = 0;
    }

    const int srow = tid >> 1;
    const int sh   = tid & 1;

    for (int ct = 0; ct < KCODES / 128; ++ct) {
        const int ctb = ct * 128;
        f32x4 acc[2][4];
        #pragma unroll
        for (int i = 0; i < 2; ++i)
            #pragma unroll
            for (int j = 0; j < 4; ++j)
                acc[i][j] = (f32x4){0.f, 0.f, 0.f, 0.f};

        #pragma unroll
        for (int c = 0; c < 4; ++c) {
            __syncthreads();
            {
                const size_t gbase = (size_t)(ctb + srow) * DIMD + c * 64 + sh * 32;
                const int lbase = srow * 72 + sh * 32;
                #pragma unroll
                for (int q = 0; q < 4; ++q) {
                    *(bf16x8*)&u.s.BsH[lbase + q * 8] = *(const bf16x8*)(Bhi + gbase + q * 8);
                    *(bf16x8*)&u.s.BsL[lbase + q * 8] = *(const bf16x8*)(Blo + gbase + q * 8);
                }
            }
            __syncthreads();
            #pragma unroll
            for (int s = 0; s < 2; ++s) {
                const int kc = c * 2 + s;
                bf16x8 bh[4], bl[4];
                #pragma unroll
                for (int j = 0; j < 4; ++j) {
                    const int br = (cb0 + j * 16 + lanem) * 72 + s * 32 + laneq * 8;
                    bh[j] = *(const bf16x8*)&u.s.BsH[br];
                    bl[j] = *(const bf16x8*)&u.s.BsL[br];
                }
                #pragma unroll
                for (int i = 0; i < 2; ++i)
                    #pragma unroll
                    for (int j = 0; j < 4; ++j) {
                        acc[i][j] = __builtin_amdgcn_mfma_f32_16x16x32_bf16(ah[i][kc], bh[j], acc[i][j], 0, 0, 0);
                        acc[i][j] = __builtin_amdgcn_mfma_f32_16x16x32_bf16(ah[i][kc], bl[j], acc[i][j], 0, 0, 0);
                        acc[i][j] = __builtin_amdgcn_mfma_f32_16x16x32_bf16(al[i][kc], bh[j], acc[i][j], 0, 0, 0);
                    }
            }
        }
        // Codes ascend within each lane slot -> strict '<' = first-min ordering.
        #pragma unroll
        for (int i = 0; i < 2; ++i)
            #pragma unroll
            for (int r = 0; r < 4; ++r) {
                const int s = i * 4 + r;
                #pragma unroll
                for (int j = 0; j < 4; ++j) {
                    const float v = acc[i][j][r];
                    const float dist = -(v + v);
                    const int code = ctb + cb0 + j * 16 + lanem;
                    if (dist < b1[s]) {
                        b3[s] = b2[s]; i3[s] = i2[s];
                        b2[s] = b1[s]; i2[s] = i1[s];
                        b1[s] = dist;  i1[s] = code;
                    } else if (dist < b2[s]) {
                        b3[s] = b2[s]; i3[s] = i2[s];
                        b2[s] = dist;  i2[s] = code;
                    } else if (dist < b3[s]) {
                        b3[s] = dist;  i3[s] = code;
                    }
                }
            }
    }

    __syncthreads();   // all LDS staging reads done -> safe to reuse union as red
    {
        const int src = (w >> 1) * 16 + lanem;
        #pragma unroll
        for (int i = 0; i < 2; ++i)
            #pragma unroll
            for (int r = 0; r < 4; ++r) {
                const int s = i * 4 + r;
                const int rr = rbase + i * 16 + laneq * 4 + r;
                const int base = rr * 97 + src * 3;
                u.r.val[base + 0] = b1[s]; u.r.idx[base + 0] = i1[s];
                u.r.val[base + 1] = b2[s]; u.r.idx[base + 1] = i2[s];
                u.r.val[base + 2] = b3[s]; u.r.idx[base + 2] = i3[s];
            }
    }
    __syncthreads();
    if (tid < 64) {
        const int base = tid * 97;
        float bd = 3.4e38f; int bi = 0x7fffffff;
        for (int t = 0; t < 96; ++t) {
            const float v = u.r.val[base + t];
            const int  ii = u.r.idx[base + t];
            if (v < bd || (v == bd && ii < bi)) { bd = v; bi = ii; }
        }
        // collect all candidates within eps of the min
        int cand[MAXC]; int nc = 0;
        const float thr = bd + FLAG_EPS;
        for (int t = 0; t < 96; ++t) {
            if (u.r.val[base + t] <= thr) {
                if (nc < MAXC) cand[nc] = u.r.idx[base + t];
                ++nc;
            }
        }
        const int row = rb + tid;
        widx[tid] = bi;
        out[OUT_IDX + (size_t)row] = (float)bi;
        if (nc >= 2) {
            if (nc <= MAXC) {
                const int pos = atomicAdd(wcount, 1);
                if (pos < CCAP) {
                    CandEntry* e = &clist[pos];
                    e->row = row; e->cnt = nc;
                    for (int q = 0; q < nc; ++q) e->codes[q] = cand[q];
                } else {
                    const int op = atomicAdd(ovfcount, 1);
                    if (op < OVFCAP) ovflist[op] = row;
                }
            } else {
                const int op = atomicAdd(ovfcount, 1);
                if (op < OVFCAP) ovflist[op] = row;
            }
        }
    }
    __syncthreads();

    // Gather z_q, write z_q_st = x + (z_q - x), accumulate loss partial.
    float lsum = 0.0f;
    const int dv = (tid & 63) * 4;
    const int rs = tid >> 6;
    const float* xblk = x + (size_t)rb * DIMD;
    float* oblk = out + (size_t)rb * DIMD;
    for (int p = 0; p < 16; ++p) {
        const int row = p * 4 + rs;
        const int wi = widx[row];
        float4 xv = *(const float4*)(xblk + (size_t)row * DIMD + dv);
        float4 cv = *(const float4*)(cb + (size_t)wi * DIMD + dv);
        const float d0 = cv.x - xv.x, d1 = cv.y - xv.y, d2 = cv.z - xv.z, d3 = cv.w - xv.w;
        float4 o;
        o.x = xv.x + d0; o.y = xv.y + d1; o.z = xv.z + d2; o.w = xv.w + d3;
        *(float4*)(oblk + (size_t)row * DIMD + dv) = o;
        lsum += d0 * d0 + d1 * d1 + d2 * d2 + d3 * d3;
    }
    #pragma unroll
    for (int off = 32; off > 0; off >>= 1) lsum += __shfl_down(lsum, off, 64);
    if ((tid & 63) == 0) wpart[tid >> 6] = lsum;
    __syncthreads();
    if (tid == 0) atomicAdd(loss_acc, wpart[0] + wpart[1] + wpart[2] + wpart[3]);
}

// One wave per flagged row; np-bin metric over <=8 candidates only.
__global__ __launch_bounds__(256) void vq_candfix_kernel(
        const float* __restrict__ x, const float* __restrict__ cb,
        float* __restrict__ out, float* __restrict__ loss_acc,
        const int* __restrict__ wcount, const CandEntry* __restrict__ clist) {
    int count = wcount[0];
    if (count > CCAP) count = CCAP;
    const int lane = threadIdx.x & 63;
    const int gw = blockIdx.x * 4 + (threadIdx.x >> 6);
    const int nw = gridDim.x * 4;
    for (int it = gw; it < count; it += nw) {
        const CandEntry* e = clist + it;
        const int row = e->row;
        const int cnt = e->cnt;
        const float4 xv = *(const float4*)(x + (size_t)row * DIMD + lane * 4);
        // Zf: fp64 sum of squares -> fp32 (grid-aligned; translation-invariance of
        // fl(Z - w) in Z by ulp multiples => same bin/tie structure as np's z_sq).
        double zs = (double)xv.x * xv.x + (double)xv.y * xv.y
                  + (double)xv.z * xv.z + (double)xv.w * xv.w;
        #pragma unroll
        for (int off = 32; off > 0; off >>= 1) zs += __shfl_xor(zs, off, 64);
        const float Zf = (float)zs;
        float bq = 3.4e38f; int bi = 0x7fffffff;
        for (int q = 0; q < cnt; ++q) {
            const int c = e->codes[q];
            const float4 cv = *(const float4*)(cb + (size_t)c * DIMD + lane * 4);
            double dp = (double)xv.x * cv.x + (double)xv.y * cv.y
                      + (double)xv.z * cv.z + (double)xv.w * cv.w;
            #pragma unroll
            for (int off = 32; off > 0; off >>= 1) dp += __shfl_xor(dp, off, 64);
            const float wv = (float)(2.0 * dp);   // np's fp32 dot (x2 exact)
            const float dq = Zf - wv;             // fp32 subtract = np's bin
            if (dq < bq || (dq == bq && c < bi)) { bq = dq; bi = c; }
        }
        const int oldi = (int)out[OUT_IDX + (size_t)row];
        if (bi != oldi) {
            const float4 cn = *(const float4*)(cb + (size_t)bi * DIMD + lane * 4);
            const float4 co = *(const float4*)(cb + (size_t)oldi * DIMD + lane * 4);
            float4 o;
            float ls = 0.0f;
            {
                const float dn = cn.x - xv.x, do_ = co.x - xv.x;
                o.x = xv.x + dn; ls += dn * dn - do_ * do_;
            }
            {
                const float dn = cn.y - xv.y, do_ = co.y - xv.y;
                o.y = xv.y + dn; ls += dn * dn - do_ * do_;
            }
            {
                const float dn = cn.z - xv.z, do_ = co.z - xv.z;
                o.z = xv.z + dn; ls += dn * dn - do_ * do_;
            }
            {
                const float dn = cn.w - xv.w, do_ = co.w - xv.w;
                o.w = xv.w + dn; ls += dn * dn - do_ * do_;
            }
            *(float4*)(out + (size_t)row * DIMD + lane * 4) = o;
            #pragma unroll
            for (int off = 32; off > 0; off >>= 1) ls += __shfl_xor(ls, off, 64);
            if (lane == 0) {
                atomicAdd(loss_acc, ls);
                out[OUT_IDX + (size_t)row] = (float)bi;
            }
        }
    }
}

// ===== full-scan fp64 fix (R3-proven) — overflow safety net + fallback path =====
__global__ __launch_bounds__(256) void vq_fix_kernel(const float* __restrict__ x,
                                                     const float* __restrict__ cb,
                                                     float* __restrict__ out,
                                                     float* __restrict__ loss_acc,
                                                     const int* __restrict__ wcount,
                                                     const int* __restrict__ wlist,
                                                     int wcap) {
    __shared__ double xd[DIMD];
    __shared__ double zred[256];
    __shared__ float  rdq[256];
    __shared__ int    ri[256];
    __shared__ float  lred[256];
    const int tid = threadIdx.x;
    int count = wcount[0];
    if (count > wcap) count = wcap;
    for (int item = blockIdx.x; item < count; item += gridDim.x) {
        const int row = wlist[item];
        const double xv0 = (double)x[(size_t)row * DIMD + tid];
        xd[tid] = xv0;
        zred[tid] = xv0 * xv0;
        __syncthreads();
        for (int st = 128; st > 0; st >>= 1) {
            if (tid < st) zred[tid] += zred[tid + st];
            __syncthreads();
        }
        const float Zf = (float)zred[0];
        float bq = 3.4e38f; int bi = 0;
        for (int c = tid; c < KCODES; c += 256) {
            const float* cr = cb + (size_t)c * DIMD;
            double s = 0.0;
            for (int d = 0; d < DIMD; d += 4) {
                float4 cv = *(const float4*)(cr + d);
                s += xd[d + 0] * (double)cv.x + xd[d + 1] * (double)cv.y
                   + xd[d + 2] * (double)cv.z + xd[d + 3] * (double)cv.w;
            }
            const float w = (float)(2.0 * s);
            const float dq = Zf - w;
            if (dq < bq) { bq = dq; bi = c; }
        }
        rdq[tid] = bq; ri[tid] = bi;
        __syncthreads();
        for (int st = 128; st > 0; st >>= 1) {
            if (tid < st) {
                const float oq = rdq[tid + st]; const int oi = ri[tid + st];
                if (oq < rdq[tid] || (oq == rdq[tid] && oi < ri[tid])) {
                    rdq[tid] = oq; ri[tid] = oi;
                }
            }
            __syncthreads();
        }
        const int newi = ri[0];
        const int oldi = (int)out[OUT_IDX + (size_t)row];
        if (newi != oldi) {
            const float xv = x[(size_t)row * DIMD + tid];
            const float co = cb[(size_t)oldi * DIMD + tid];
            const float cn = cb[(size_t)newi * DIMD + tid];
            const float dold = co - xv, dnew = cn - xv;
            out[(size_t)row * DIMD + tid] = xv + dnew;
            lred[tid] = dnew * dnew - dold * dold;
        } else {
            lred[tid] = 0.0f;
        }
        __syncthreads();
        for (int st = 128; st > 0; st >>= 1) {
            if (tid < st) lred[tid] += lred[tid + st];
            __syncthreads();
        }
        if (tid == 0 && newi != oldi) {
            atomicAdd(loss_acc, lred[0]);
            out[OUT_IDX + (size_t)row] = (float)newi;
        }
        __syncthreads();
    }
}

__global__ void finalize_kernel(const float* __restrict__ loss_acc, float* __restrict__ out) {
    if (threadIdx.x == 0 && blockIdx.x == 0)
        out[OUT_LOSS] = 1.25f * (loss_acc[0] / 8388608.0f);
}

// ===== fallback fp32 screen (R3-proven) for small ws_size =====
#define MT 128
#define DK 32
#define LSTR 130
__global__ __launch_bounds__(256) void vq_main_fp32_kernel(const float* __restrict__ x,
                                                           const float* __restrict__ cb,
                                                           float* __restrict__ out,
                                                           float* __restrict__ loss_acc,
                                                           int* __restrict__ wcount,
                                                           int* __restrict__ wlist,
                                                           int wcap) {
    __shared__ float As[DK * LSTR];
    __shared__ float Bs[DK * LSTR];
    __shared__ float red_d[MT * 17];
    __shared__ float red_2[MT * 17];
    __shared__ int   red_i[MT * 17];
    __shared__ int   widx[MT];
    __shared__ float wpart[4];
    const int tid = threadIdx.x;
    const int tx = tid & 15;
    const int ty = tid >> 4;
    const float* xblk = x + (size_t)blockIdx.x * MT * DIMD;
    float b1[8], b2[8]; int i1[8];
    #pragma unroll
    for (int i = 0; i < 8; ++i) { b1[i] = 3.4e38f; b2[i] = 3.4e38f; i1[i] = 0; }
    const int sr = tid >> 3;
    const int sd = (tid & 7) * 4;
    for (int kt = 0; kt < KCODES; kt += 128) {
        float acc[8][8];
        #pragma unroll
        for (int i = 0; i < 8; ++i)
            #pragma unroll
            for (int j = 0; j < 8; ++j) acc[i][j] = 0.0f;
        const float* bblk = cb + (size_t)kt * DIMD;
        for (int dc = 0; dc < DIMD; dc += DK) {
            __syncthreads();
            #pragma unroll
            for (int p = 0; p < 4; ++p) {
                const int r = p * 32 + sr;
                float4 va = *(const float4*)(xblk + (size_t)r * DIMD + dc + sd);
                float4 vb = *(const float4*)(bblk + (size_t)r * DIMD + dc + sd);
                As[(sd + 0) * LSTR + r] = va.x; As[(sd + 1) * LSTR + r] = va.y;
                As[(sd + 2) * LSTR + r] = va.z; As[(sd + 3) * LSTR + r] = va.w;
                Bs[(sd + 0) * LSTR + r] = vb.x; Bs[(sd + 1) * LSTR + r] = vb.y;
                Bs[(sd + 2) * LSTR + r] = vb.z; Bs[(sd + 3) * LSTR + r] = vb.w;
            }
            __syncthreads();
            #pragma unroll 4
            for (int d = 0; d < DK; ++d) {
                const float2* ap = (const float2*)&As[d * LSTR + ty * 8];
                const float2* bp = (const float2*)&Bs[d * LSTR + tx * 8];
                float2 a0 = ap[0], a1 = ap[1], a2 = ap[2], a3 = ap[3];
                float2 c0 = bp[0], c1 = bp[1], c2 = bp[2], c3 = bp[3];
                float a[8] = {a0.x, a0.y, a1.x, a1.y, a2.x, a2.y, a3.x, a3.y};
                float b[8] = {c0.x, c0.y, c1.x, c1.y, c2.x, c2.y, c3.x, c3.y};
                #pragma unroll
                for (int i = 0; i < 8; ++i)
                    #pragma unroll
                    for (int j = 0; j < 8; ++j)
                        acc[i][j] += a[i] * b[j];
            }
        }
        #pragma unroll
        for (int j = 0; j < 8; ++j) {
            const int code = kt + tx * 8 + j;
            #pragma unroll
            for (int i = 0; i < 8; ++i) {
                const float dist = -(acc[i][j] + acc[i][j]);
                if (dist < b1[i]) { b2[i] = b1[i]; b1[i] = dist; i1[i] = code; }
                else if (dist < b2[i]) b2[i] = dist;
            }
        }
    }
    __syncthreads();
    #pragma unroll
    for (int i = 0; i < 8; ++i) {
        red_d[(ty * 8 + i) * 17 + tx] = b1[i];
        red_2[(ty * 8 + i) * 17 + tx] = b2[i];
        red_i[(ty * 8 + i) * 17 + tx] = i1[i];
    }
    __syncthreads();
    if (tid < MT) {
        float bd = red_d[tid * 17];
        float s2 = red_2[tid * 17];
        int   bi = red_i[tid * 17];
        #pragma unroll
        for (int t = 1; t < 16; ++t) {
            const float d1 = red_d[tid * 17 + t];
            const float d2 = red_2[tid * 17 + t];
            const int   ii = red_i[tid * 17 + t];
            if (d1 < bd || (d1 == bd && ii < bi)) { s2 = fminf(bd, d2); bd = d1; bi = ii; }
            else s2 = fminf(s2, d1);
        }
        const int row = blockIdx.x * MT + tid;
        widx[tid] = bi;
        out[OUT_IDX + (size_t)row] = (float)bi;
        if (s2 - bd <= FLAG_EPS) {
            const int pos = atomicAdd(wcount, 1);
            if (pos < wcap) wlist[pos] = row;
        }
    }
    __syncthreads();
    float lsum = 0.0f;
    const int dv = (tid & 63) * 4;
    const int rs = tid >> 6;
    float* oblk = out + (size_t)blockIdx.x * MT * DIMD;
    for (int p = 0; p < 32; ++p) {
        const int row = p * 4 + rs;
        const int wi = widx[row];
        float4 xv = *(const float4*)(xblk + (size_t)row * DIMD + dv);
        float4 cv = *(const float4*)(cb + (size_t)wi * DIMD + dv);
        const float d0 = cv.x - xv.x, d1 = cv.y - xv.y, d2 = cv.z - xv.z, d3 = cv.w - xv.w;
        float4 o;
        o.x = xv.x + d0; o.y = xv.y + d1; o.z = xv.z + d2; o.w = xv.w + d3;
        *(float4*)(oblk + (size_t)row * DIMD + dv) = o;
        lsum += d0 * d0 + d1 * d1 + d2 * d2 + d3 * d3;
    }
    #pragma unroll
    for (int off = 32; off > 0; off >>= 1) lsum += __shfl_down(lsum, off, 64);
    if ((tid & 63) == 0) wpart[tid >> 6] = lsum;
    __syncthreads();
    if (tid == 0) atomicAdd(loss_acc, wpart[0] + wpart[1] + wpart[2] + wpart[3]);
}

extern "C" void kernel_launch(void* const* d_in, const int* in_sizes, int n_in,
                              void* d_out, int out_size, void* d_ws, size_t ws_size,
                              hipStream_t stream) {
    const float* x  = (const float*)d_in[0];
    const float* cb = (const float*)d_in[1];
    float* out = (float*)d_out;
    float* loss_acc = (float*)d_ws;
    int*   wcount   = (int*)((char*)d_ws + 32);
    int*   ovfcount = (int*)((char*)d_ws + 36);
    CandEntry* clist = (CandEntry*)((char*)d_ws + WS_CLIST);
    int*   ovflist  = (int*)((char*)d_ws + WS_OVF);

    init_kernel<<<1, 64, 0, stream>>>(loss_acc, wcount, ovfcount);
    if (ws_size >= (size_t)WS_END) {
        unsigned short* Ahi = (unsigned short*)((char*)d_ws + WS_AHI);
        unsigned short* Alo = (unsigned short*)((char*)d_ws + WS_ALO);
        unsigned short* Bhi = (unsigned short*)((char*)d_ws + WS_BHI);
        unsigned short* Blo = (unsigned short*)((char*)d_ws + WS_BLO);
        convert_kernel<<<8192, 256, 0, stream>>>(x, Ahi, Alo);
        convert_kernel<<<1024, 256, 0, stream>>>(cb, Bhi, Blo);
        vq_screen_kernel<<<512, 256, 0, stream>>>(Ahi, Alo, Bhi, Blo, x, cb, out,
                                                  loss_acc, wcount, clist,
                                                  ovfcount, ovflist);
        vq_candfix_kernel<<<256, 256, 0, stream>>>(x, cb, out, loss_acc, wcount, clist);
        vq_fix_kernel<<<64, 256, 0, stream>>>(x, cb, out, loss_acc, ovfcount, ovflist, OVFCAP);
    } else {
        int* wlist = (int*)((char*)d_ws + WS_CLIST);
        int wcap = 0;
        if (ws_size > WS_CLIST + sizeof(int)) {
            size_t c = (ws_size - WS_CLIST) / sizeof(int);
            wcap = (int)(c > 32768 ? 32768 : c);
        }
        vq_main_fp32_kernel<<<256, 256, 0, stream>>>(x, cb, out, loss_acc,
                                                     wcount, wlist, wcap);
        vq_fix_kernel<<<512, 256, 0, stream>>>(x, cb, out, loss_acc, wcount, wlist, wcap);
    }
    finalize_kernel<<<1, 1, 0, stream>>>(loss_acc, out);
}

// Round 6
// 427.904 us; speedup vs baseline: 4.0020x; 1.4633x over previous
//
#include <hip/hip_runtime.h>

// VectorQuantizer: x [8,16,256,256] fp32 -> N=32768 rows, D=256; codebook K=4096 x 256.
// d_out flat (read back as float32):
//   [0 .. 8388608)   z_q_st  (= codebook[argmin])
//   [8388608]        loss = 1.25 * mean((z_q - x)^2)
//   [8388609 ..)     encoding indices, written as float values
//
// R6 pipeline:
//   convertB: codebook fp32 -> bf16 hi plane (2 MB).
//   screen:   1-term bf16 MFMA GEMM on -2*dot (A=bf16(x) built in-reg from fp32).
//             Scores packed as u32 key = qdist<<12 | code (qstep 3.66e-6), per-lane
//             top-2 via v_min/max_u32 -> key-min == (dist, first-index) lex-min.
//             Rows with >=2 keys within EPSQ of min -> candidate list; lanes whose
//             BOTH top-2 are within threshold may hide a 3rd -> overflow list.
//   candfix:  one wave per flagged row, np-bin metric fl32(Zf - fl32(2*dot64)) over
//             <=8 candidates, (dq, idx)-lex first-min.  [R3/R5-proven numerics]
//   ovf:      full 4096-code rescan, thread-per-code, same np-bin metric.
// Error budget: 1-term bf16 screen err per dot <= ~2e-5 (Hoeffding e-43 at 4e-5);
// np bin width = ulp(z_sq) <= 3.05e-5; qstep slop 2*3.66e-6. EPSQ=40 (1.46e-4) covers
// everything with >2x margin. Flag rate ~13%; all flagged rows resolved exactly.
typedef __attribute__((ext_vector_type(8))) short bf16x8;
typedef __attribute__((ext_vector_type(4))) float f32x4;

#define DIMD 256
#define KCODES 4096
#define NROWS 32768
#define OUT_LOSS 8388608
#define OUT_IDX  8388609
#define MAXC 8
#define EPSQ 40u              // candidate window in qsteps (40*3.66e-6 = 1.46e-4)
#define QSCALE 273066.67f     // 65536/0.24 : qdist = (dist + 0.12) * QSCALE
#define QBIAS  0.12f

struct CandEntry { int row; int cnt; int codes[MAXC]; };   // 40 B

// ws layout (bytes): loss f32 @0 | wcount i32 @32 | ovfcount i32 @36 |
// clist @4096 (16384 x 40 B = 655360) | ovflist @659456 (8192 i32) |
// Bhi @1MB (4096*256*2 = 2 MB)
#define WS_CLIST 4096u
#define CCAP     16384
#define WS_OVF   659456u
#define OVFCAP   8192
#define WS_BHI   (1024u*1024u)
#define WS_END   (WS_BHI + (unsigned)KCODES*DIMD*2u)   // 3,145,728

__device__ __forceinline__ unsigned short bf16_rne(float f) {
    unsigned u = __float_as_uint(f);
    u += 0x7FFFu + ((u >> 16) & 1u);
    return (unsigned short)(u >> 16);
}

__global__ void init_kernel(float* __restrict__ loss_acc, int* __restrict__ wcount,
                            int* __restrict__ ovfcount) {
    if (threadIdx.x == 0) { loss_acc[0] = 0.0f; wcount[0] = 0; ovfcount[0] = 0; }
}

__global__ __launch_bounds__(256) void convertB_kernel(const float* __restrict__ src,
                                                       unsigned short* __restrict__ hi) {
    const size_t e = ((size_t)blockIdx.x * 256 + threadIdx.x) * 4;
    float4 v = *(const float4*)(src + e);
    ushort4 h;
    h.x = bf16_rne(v.x); h.y = bf16_rne(v.y);
    h.z = bf16_rne(v.z); h.w = bf16_rne(v.w);
    *(ushort4*)(hi + e) = h;
}

// LDS union: B staging (K loop) then key-reduction array (post loop). 18,432 B.
struct ScreenStage { short Bs[128 * 72]; };                 // RS=72 shorts (144 B)
struct ScreenRed   { unsigned key[64 * 65]; };              // [row][lane*2+slot]
union ScreenLds { ScreenStage s; ScreenRed r; };

__global__ __launch_bounds__(256, 2) void vq_screen_kernel(
        const unsigned short* __restrict__ Bhi,
        const float* __restrict__ x, const float* __restrict__ cb,
        float* __restrict__ out, float* __restrict__ loss_acc,
        int* __restrict__ wcount, CandEntry* __restrict__ clist,
        int* __restrict__ ovfcount, int* __restrict__ ovflist) {
    __shared__ ScreenLds u;
    __shared__ int   widx[64];
    __shared__ float wpart[4];

    const int tid   = threadIdx.x;
    const int w     = tid >> 6;
    const int lane  = tid & 63;
    const int lanem = lane & 15;
    const int laneq = lane >> 4;
    const int rbase = (w & 1) * 32;      // wave row base (2 row-groups)
    const int cb0   = (w >> 1) * 64;     // wave col base (2 col-groups)
    const int rb    = blockIdx.x * 64;

    // Persistent A fragments built in-register from fp32 x (no Ahi plane needed).
    bf16x8 ah[2][8];
    #pragma unroll
    for (int i = 0; i < 2; ++i) {
        const float* xrow = x + (size_t)(rb + rbase + i * 16 + lanem) * DIMD;
        #pragma unroll
        for (int kc = 0; kc < 8; ++kc) {
            float4 f0 = *(const float4*)(xrow + kc * 32 + laneq * 8);
            float4 f1 = *(const float4*)(xrow + kc * 32 + laneq * 8 + 4);
            bf16x8 v;
            v[0] = (short)bf16_rne(f0.x); v[1] = (short)bf16_rne(f0.y);
            v[2] = (short)bf16_rne(f0.z); v[3] = (short)bf16_rne(f0.w);
            v[4] = (short)bf16_rne(f1.x); v[5] = (short)bf16_rne(f1.y);
            v[6] = (short)bf16_rne(f1.z); v[7] = (short)bf16_rne(f1.w);
            ah[i][kc] = v;
        }
    }

    // Per-lane/slot top-2 packed keys (u32): qdist<<12 | code.
    unsigned b1[8], b2[8];
    #pragma unroll
    for (int s = 0; s < 8; ++s) { b1[s] = 0xFFFFFFFFu; b2[s] = 0xFFFFFFFFu; }

    const int srow = tid >> 1;           // staging code-row 0..127
    const int sh   = tid & 1;            // k-half of 64-k chunk

    for (int ct = 0; ct < KCODES / 128; ++ct) {
        const int ctb = ct * 128;
        f32x4 acc[2][4];
        #pragma unroll
        for (int i = 0; i < 2; ++i)
            #pragma unroll
            for (int j = 0; j < 4; ++j)
                acc[i][j] = (f32x4){0.f, 0.f, 0.f, 0.f};

        #pragma unroll
        for (int c = 0; c < 4; ++c) {    // BK=64 chunks
            __syncthreads();
            {
                const size_t gbase = (size_t)(ctb + srow) * DIMD + c * 64 + sh * 32;
                const int lbase = srow * 72 + sh * 32;
                #pragma unroll
                for (int q = 0; q < 4; ++q)
                    *(bf16x8*)&u.s.Bs[lbase + q * 8] = *(const bf16x8*)(Bhi + gbase + q * 8);
            }
            __syncthreads();
            #pragma unroll
            for (int s = 0; s < 2; ++s) {
                const int kc = c * 2 + s;
                bf16x8 bh[4];
                #pragma unroll
                for (int j = 0; j < 4; ++j)
                    bh[j] = *(const bf16x8*)&u.s.Bs[(cb0 + j * 16 + lanem) * 72 + s * 32 + laneq * 8];
                #pragma unroll
                for (int i = 0; i < 2; ++i)
                    #pragma unroll
                    for (int j = 0; j < 4; ++j)
                        acc[i][j] = __builtin_amdgcn_mfma_f32_16x16x32_bf16(ah[i][kc], bh[j], acc[i][j], 0, 0, 0);
            }
        }
        // dist = -2*acc; key = (u32)((dist+QBIAS)*QSCALE)<<12 | code. Branchless
        // top-2 via unsigned min/max; ascending codes => key-min == first-index min.
        #pragma unroll
        for (int j = 0; j < 4; ++j) {
            const unsigned code = (unsigned)(ctb + cb0 + j * 16 + lanem);
            #pragma unroll
            for (int i = 0; i < 2; ++i)
                #pragma unroll
                for (int r = 0; r < 4; ++r) {
                    const int s = i * 4 + r;
                    const float dist = fmaf(acc[i][j][r], -2.0f * QSCALE, QBIAS * QSCALE);
                    const unsigned k = ((unsigned)dist << 12) | code;
                    const unsigned lo = min(b1[s], k);
                    const unsigned hi = max(b1[s], k);
                    b1[s] = lo;
                    b2[s] = min(b2[s], hi);
                }
        }
    }

    __syncthreads();   // staging reads done -> reuse union as reduction array
    {
        const int src = (w >> 1) * 16 + lanem;   // 0..31 candidate columns per row
        #pragma unroll
        for (int i = 0; i < 2; ++i)
            #pragma unroll
            for (int r = 0; r < 4; ++r) {
                const int s = i * 4 + r;
                const int rr = rbase + i * 16 + laneq * 4 + r;
                u.r.key[rr * 65 + src * 2 + 0] = b1[s];
                u.r.key[rr * 65 + src * 2 + 1] = b2[s];
            }
    }
    __syncthreads();
    if (tid < 64) {
        const int base = tid * 65;
        unsigned kmin = 0xFFFFFFFFu;
        for (int t = 0; t < 64; ++t) kmin = min(kmin, u.r.key[base + t]);
        const unsigned thr = (((kmin >> 12) + EPSQ) << 12) | 0xFFFu;
        int cand[MAXC]; int nc = 0; int ovf = 0;
        for (int L = 0; L < 32; ++L) {
            const unsigned v0 = u.r.key[base + L * 2 + 0];
            const unsigned v1 = u.r.key[base + L * 2 + 1];
            if (v0 <= thr) {
                if (nc < MAXC) cand[nc] = (int)(v0 & 0xFFFu);
                ++nc;
                if (v1 <= thr) {          // lane's 3rd-best unknown -> conservative
                    if (nc < MAXC) cand[nc] = (int)(v1 & 0xFFFu);
                    ++nc;
                    ovf = 1;
                }
            }
        }
        const int row = rb + tid;
        const int bi = (int)(kmin & 0xFFFu);
        widx[tid] = bi;
        out[OUT_IDX + (size_t)row] = (float)bi;
        if (ovf || nc > MAXC) {
            const int op = atomicAdd(ovfcount, 1);
            if (op < OVFCAP) ovflist[op] = row;
        } else if (nc >= 2) {
            const int pos = atomicAdd(wcount, 1);
            if (pos < CCAP) {
                CandEntry* e = &clist[pos];
                e->row = row; e->cnt = nc;
                for (int q = 0; q < nc; ++q) e->codes[q] = cand[q];
            } else {
                const int op = atomicAdd(ovfcount, 1);
                if (op < OVFCAP) ovflist[op] = row;
            }
        }
    }
    __syncthreads();

    // Gather z_q, write z_q_st = x + (z_q - x), accumulate loss partial.
    float lsum = 0.0f;
    const int dv = (tid & 63) * 4;
    const int rs = tid >> 6;
    const float* xblk = x + (size_t)rb * DIMD;
    float* oblk = out + (size_t)rb * DIMD;
    for (int p = 0; p < 16; ++p) {
        const int row = p * 4 + rs;
        const int wi = widx[row];
        float4 xv = *(const float4*)(xblk + (size_t)row * DIMD + dv);
        float4 cv = *(const float4*)(cb + (size_t)wi * DIMD + dv);
        const float d0 = cv.x - xv.x, d1 = cv.y - xv.y, d2 = cv.z - xv.z, d3 = cv.w - xv.w;
        float4 o;
        o.x = xv.x + d0; o.y = xv.y + d1; o.z = xv.z + d2; o.w = xv.w + d3;
        *(float4*)(oblk + (size_t)row * DIMD + dv) = o;
        lsum += d0 * d0 + d1 * d1 + d2 * d2 + d3 * d3;
    }
    #pragma unroll
    for (int off = 32; off > 0; off >>= 1) lsum += __shfl_down(lsum, off, 64);
    if ((tid & 63) == 0) wpart[tid >> 6] = lsum;
    __syncthreads();
    if (tid == 0) atomicAdd(loss_acc, wpart[0] + wpart[1] + wpart[2] + wpart[3]);
}

// One wave per flagged row; np-bin metric over <=8 candidates. [R5-proven]
__global__ __launch_bounds__(256) void vq_candfix_kernel(
        const float* __restrict__ x, const float* __restrict__ cb,
        float* __restrict__ out, float* __restrict__ loss_acc,
        const int* __restrict__ wcount, const CandEntry* __restrict__ clist) {
    int count = wcount[0];
    if (count > CCAP) count = CCAP;
    const int lane = threadIdx.x & 63;
    const int gw = blockIdx.x * 4 + (threadIdx.x >> 6);
    const int nw = gridDim.x * 4;
    for (int it = gw; it < count; it += nw) {
        const CandEntry* e = clist + it;
        const int row = e->row;
        const int cnt = e->cnt;
        const float4 xv = *(const float4*)(x + (size_t)row * DIMD + lane * 4);
        double zs = (double)xv.x * xv.x + (double)xv.y * xv.y
                  + (double)xv.z * xv.z + (double)xv.w * xv.w;
        #pragma unroll
        for (int off = 32; off > 0; off >>= 1) zs += __shfl_xor(zs, off, 64);
        const float Zf = (float)zs;   // grid-aligned z_sq (translation-invariance)
        float bq = 3.4e38f; int bi = 0x7fffffff;
        for (int q = 0; q < cnt; ++q) {
            const int c = e->codes[q];
            const float4 cv = *(const float4*)(cb + (size_t)c * DIMD + lane * 4);
            double dp = (double)xv.x * cv.x + (double)xv.y * cv.y
                      + (double)xv.z * cv.z + (double)xv.w * cv.w;
            #pragma unroll
            for (int off = 32; off > 0; off >>= 1) dp += __shfl_xor(dp, off, 64);
            const float wv = (float)(2.0 * dp);
            const float dq = Zf - wv;             // fp32 subtract = np's bin
            if (dq < bq || (dq == bq && c < bi)) { bq = dq; bi = c; }
        }
        const int oldi = (int)out[OUT_IDX + (size_t)row];
        if (bi != oldi) {
            const float4 cn = *(const float4*)(cb + (size_t)bi * DIMD + lane * 4);
            const float4 co = *(const float4*)(cb + (size_t)oldi * DIMD + lane * 4);
            float4 o; float ls = 0.0f;
            { const float dn = cn.x - xv.x, dd = co.x - xv.x; o.x = xv.x + dn; ls += dn*dn - dd*dd; }
            { const float dn = cn.y - xv.y, dd = co.y - xv.y; o.y = xv.y + dn; ls += dn*dn - dd*dd; }
            { const float dn = cn.z - xv.z, dd = co.z - xv.z; o.z = xv.z + dn; ls += dn*dn - dd*dd; }
            { const float dn = cn.w - xv.w, dd = co.w - xv.w; o.w = xv.w + dn; ls += dn*dn - dd*dd; }
            *(float4*)(out + (size_t)row * DIMD + lane * 4) = o;
            #pragma unroll
            for (int off = 32; off > 0; off >>= 1) ls += __shfl_xor(ls, off, 64);
            if (lane == 0) {
                atomicAdd(loss_acc, ls);
                out[OUT_IDX + (size_t)row] = (float)bi;
            }
        }
    }
}

// Overflow rows: full 4096-code rescan, thread-per-code, np-bin metric.
__global__ __launch_bounds__(256) void vq_ovf_kernel(
        const float* __restrict__ x, const float* __restrict__ cb,
        float* __restrict__ out, float* __restrict__ loss_acc,
        const int* __restrict__ ovfcount, const int* __restrict__ ovflist) {
    __shared__ double xd[DIMD];
    __shared__ double zred[256];
    __shared__ float  rdq[256];
    __shared__ int    ri[256];
    __shared__ float  lred[256];
    const int tid = threadIdx.x;
    int count = ovfcount[0];
    if (count > OVFCAP) count = OVFCAP;
    for (int item = blockIdx.x; item < count; item += gridDim.x) {
        const int row = ovflist[item];
        const double xv0 = (double)x[(size_t)row * DIMD + tid];
        xd[tid] = xv0;
        zred[tid] = xv0 * xv0;
        __syncthreads();
        for (int st = 128; st > 0; st >>= 1) {
            if (tid < st) zred[tid] += zred[tid + st];
            __syncthreads();
        }
        const float Zf = (float)zred[0];
        float bq = 3.4e38f; int bi = 0x7fffffff;
        for (int q = 0; q < 16; ++q) {         // thread's codes ascend: q*256+tid
            const int c = q * 256 + tid;
            const float* cr = cb + (size_t)c * DIMD;
            double s = 0.0;
            for (int d = 0; d < DIMD; d += 4) {
                float4 cv = *(const float4*)(cr + d);
                s += xd[d + 0] * (double)cv.x + xd[d + 1] * (double)cv.y
                   + xd[d + 2] * (double)cv.z + xd[d + 3] * (double)cv.w;
            }
            const float wv = (float)(2.0 * s);
            const float dq = Zf - wv;
            if (dq < bq || (dq == bq && c < bi)) { bq = dq; bi = c; }
        }
        rdq[tid] = bq; ri[tid] = bi;
        __syncthreads();
        for (int st = 128; st > 0; st >>= 1) {
            if (tid < st) {
                const float oq = rdq[tid + st]; const int oi = ri[tid + st];
                if (oq < rdq[tid] || (oq == rdq[tid] && oi < ri[tid])) {
                    rdq[tid] = oq; ri[tid] = oi;
                }
            }
            __syncthreads();
        }
        const int newi = ri[0];
        const int oldi = (int)out[OUT_IDX + (size_t)row];
        if (newi != oldi) {
            const float xv = x[(size_t)row * DIMD + tid];
            const float co = cb[(size_t)oldi * DIMD + tid];
            const float cn = cb[(size_t)newi * DIMD + tid];
            const float dold = co - xv, dnew = cn - xv;
            out[(size_t)row * DIMD + tid] = xv + dnew;
            lred[tid] = dnew * dnew - dold * dold;
        } else {
            lred[tid] = 0.0f;
        }
        __syncthreads();
        for (int st = 128; st > 0; st >>= 1) {
            if (tid < st) lred[tid] += lred[tid + st];
            __syncthreads();
        }
        if (tid == 0 && newi != oldi) {
            atomicAdd(loss_acc, lred[0]);
            out[OUT_IDX + (size_t)row] = (float)newi;
        }
        __syncthreads();
    }
}

__global__ void finalize_kernel(const float* __restrict__ loss_acc, float* __restrict__ out) {
    if (threadIdx.x == 0 && blockIdx.x == 0)
        out[OUT_LOSS] = 1.25f * (loss_acc[0] / 8388608.0f);
}

// ===== fallback fp32 path (R3-proven) for small ws_size =====
#define MT 128
#define DK 32
#define LSTR 130
#define FLAG_EPS_F32 3.6e-5f
__global__ __launch_bounds__(256) void vq_main_fp32_kernel(const float* __restrict__ x,
                                                           const float* __restrict__ cb,
                                                           float* __restrict__ out,
                                                           float* __restrict__ loss_acc,
                                                           int* __restrict__ wcount,
                                                           int* __restrict__ wlist,
                                                           int wcap) {
    __shared__ float As[DK * LSTR];
    __shared__ float Bs[DK * LSTR];
    __shared__ float red_d[MT * 17];
    __shared__ float red_2[MT * 17];
    __shared__ int   red_i[MT * 17];
    __shared__ int   widx[MT];
    __shared__ float wpart[4];
    const int tid = threadIdx.x;
    const int tx = tid & 15;
    const int ty = tid >> 4;
    const float* xblk = x + (size_t)blockIdx.x * MT * DIMD;
    float b1[8], b2[8]; int i1[8];
    #pragma unroll
    for (int i = 0; i < 8; ++i) { b1[i] = 3.4e38f; b2[i] = 3.4e38f; i1[i] = 0; }
    const int sr = tid >> 3;
    const int sd = (tid & 7) * 4;
    for (int kt = 0; kt < KCODES; kt += 128) {
        float acc[8][8];
        #pragma unroll
        for (int i = 0; i < 8; ++i)
            #pragma unroll
            for (int j = 0; j < 8; ++j) acc[i][j] = 0.0f;
        const float* bblk = cb + (size_t)kt * DIMD;
        for (int dc = 0; dc < DIMD; dc += DK) {
            __syncthreads();
            #pragma unroll
            for (int p = 0; p < 4; ++p) {
                const int r = p * 32 + sr;
                float4 va = *(const float4*)(xblk + (size_t)r * DIMD + dc + sd);
                float4 vb = *(const float4*)(bblk + (size_t)r * DIMD + dc + sd);
                As[(sd + 0) * LSTR + r] = va.x; As[(sd + 1) * LSTR + r] = va.y;
                As[(sd + 2) * LSTR + r] = va.z; As[(sd + 3) * LSTR + r] = va.w;
                Bs[(sd + 0) * LSTR + r] = vb.x; Bs[(sd + 1) * LSTR + r] = vb.y;
                Bs[(sd + 2) * LSTR + r] = vb.z; Bs[(sd + 3) * LSTR + r] = vb.w;
            }
            __syncthreads();
            #pragma unroll 4
            for (int d = 0; d < DK; ++d) {
                const float2* ap = (const float2*)&As[d * LSTR + ty * 8];
                const float2* bp = (const float2*)&Bs[d * LSTR + tx * 8];
                float2 a0 = ap[0], a1 = ap[1], a2 = ap[2], a3 = ap[3];
                float2 c0 = bp[0], c1 = bp[1], c2 = bp[2], c3 = bp[3];
                float a[8] = {a0.x, a0.y, a1.x, a1.y, a2.x, a2.y, a3.x, a3.y};
                float b[8] = {c0.x, c0.y, c1.x, c1.y, c2.x, c2.y, c3.x, c3.y};
                #pragma unroll
                for (int i = 0; i < 8; ++i)
                    #pragma unroll
                    for (int j = 0; j < 8; ++j)
                        acc[i][j] += a[i] * b[j];
            }
        }
        #pragma unroll
        for (int j = 0; j < 8; ++j) {
            const int code = kt + tx * 8 + j;
            #pragma unroll
            for (int i = 0; i < 8; ++i) {
                const float dist = -(acc[i][j] + acc[i][j]);
                if (dist < b1[i]) { b2[i] = b1[i]; b1[i] = dist; i1[i] = code; }
                else if (dist < b2[i]) b2[i] = dist;
            }
        }
    }
    __syncthreads();
    #pragma unroll
    for (int i = 0; i < 8; ++i) {
        red_d[(ty * 8 + i) * 17 + tx] = b1[i];
        red_2[(ty * 8 + i) * 17 + tx] = b2[i];
        red_i[(ty * 8 + i) * 17 + tx] = i1[i];
    }
    __syncthreads();
    if (tid < MT) {
        float bd = red_d[tid * 17];
        float s2 = red_2[tid * 17];
        int   bi = red_i[tid * 17];
        #pragma unroll
        for (int t = 1; t < 16; ++t) {
            const float d1 = red_d[tid * 17 + t];
            const float d2 = red_2[tid * 17 + t];
            const int   ii = red_i[tid * 17 + t];
            if (d1 < bd || (d1 == bd && ii < bi)) { s2 = fminf(bd, d2); bd = d1; bi = ii; }
            else s2 = fminf(s2, d1);
        }
        const int row = blockIdx.x * MT + tid;
        widx[tid] = bi;
        out[OUT_IDX + (size_t)row] = (float)bi;
        if (s2 - bd <= FLAG_EPS_F32) {
            const int pos = atomicAdd(wcount, 1);
            if (pos < wcap) wlist[pos] = row;
        }
    }
    __syncthreads();
    float lsum = 0.0f;
    const int dv = (tid & 63) * 4;
    const int rs = tid >> 6;
    float* oblk = out + (size_t)blockIdx.x * MT * DIMD;
    for (int p = 0; p < 32; ++p) {
        const int row = p * 4 + rs;
        const int wi = widx[row];
        float4 xv = *(const float4*)(xblk + (size_t)row * DIMD + dv);
        float4 cv = *(const float4*)(cb + (size_t)wi * DIMD + dv);
        const float d0 = cv.x - xv.x, d1 = cv.y - xv.y, d2 = cv.z - xv.z, d3 = cv.w - xv.w;
        float4 o;
        o.x = xv.x + d0; o.y = xv.y + d1; o.z = xv.z + d2; o.w = xv.w + d3;
        *(float4*)(oblk + (size_t)row * DIMD + dv) = o;
        lsum += d0 * d0 + d1 * d1 + d2 * d2 + d3 * d3;
    }
    #pragma unroll
    for (int off = 32; off > 0; off >>= 1) lsum += __shfl_down(lsum, off, 64);
    if ((tid & 63) == 0) wpart[tid >> 6] = lsum;
    __syncthreads();
    if (tid == 0) atomicAdd(loss_acc, wpart[0] + wpart[1] + wpart[2] + wpart[3]);
}

extern "C" void kernel_launch(void* const* d_in, const int* in_sizes, int n_in,
                              void* d_out, int out_size, void* d_ws, size_t ws_size,
                              hipStream_t stream) {
    const float* x  = (const float*)d_in[0];
    const float* cb = (const float*)d_in[1];
    float* out = (float*)d_out;
    float* loss_acc = (float*)d_ws;
    int*   wcount   = (int*)((char*)d_ws + 32);
    int*   ovfcount = (int*)((char*)d_ws + 36);
    CandEntry* clist = (CandEntry*)((char*)d_ws + WS_CLIST);
    int*   ovflist  = (int*)((char*)d_ws + WS_OVF);

    init_kernel<<<1, 64, 0, stream>>>(loss_acc, wcount, ovfcount);
    if (ws_size >= (size_t)WS_END) {
        unsigned short* Bhi = (unsigned short*)((char*)d_ws + WS_BHI);
        convertB_kernel<<<1024, 256, 0, stream>>>(cb, Bhi);
        vq_screen_kernel<<<512, 256, 0, stream>>>(Bhi, x, cb, out, loss_acc,
                                                  wcount, clist, ovfcount, ovflist);
        vq_candfix_kernel<<<512, 256, 0, stream>>>(x, cb, out, loss_acc, wcount, clist);
        vq_ovf_kernel<<<256, 256, 0, stream>>>(x, cb, out, loss_acc, ovfcount, ovflist);
    } else {
        int* wlist = (int*)((char*)d_ws + WS_CLIST);
        int wcap = 0;
        if (ws_size > WS_CLIST + sizeof(int)) {
            size_t c = (ws_size - WS_CLIST) / sizeof(int);
            wcap = (int)(c > 32768 ? 32768 : c);
        }
        vq_main_fp32_kernel<<<256, 256, 0, stream>>>(x, cb, out, loss_acc,
                                                     wcount, wlist, wcap);
        vq_ovf_kernel<<<512, 256, 0, stream>>>(x, cb, out, loss_acc, wcount, wlist);
    }
    finalize_kernel<<<1, 1, 0, stream>>>(loss_acc, out);
}

// Round 7
// 341.489 us; speedup vs baseline: 5.0147x; 1.2531x over previous
//
#include <hip/hip_runtime.h>

// VectorQuantizer: x [8,16,256,256] fp32 -> N=32768 rows, D=256; codebook K=4096 x 256.
// d_out flat (read back as float32):
//   [0 .. 8388608)   z_q_st  (= codebook[argmin])
//   [8388608]        loss = 1.25 * mean((z_q - x)^2)
//   [8388609 ..)     encoding indices, written as float values
//
// R7 pipeline:
//   convertB: codebook fp32 -> bf16 plane (2 MB, L2-resident).
//   screen:   barrier-free 1-term bf16 MFMA GEMM on -2*dot. B frags loaded
//             straight from L2 to registers (no LDS staging, no K-loop barriers).
//             Scores packed u32 key = qdist<<12 | code; per-lane TOP-3 via
//             min/max chains -> key-min == (dist, first-index) lex-min.
//             Row-owner collects all keys within EPSQ of min: 1 -> done,
//             2..8 -> candidate list, lane-saturated (3 in one column) or >8
//             -> overflow list (full rescan).
//   candfix:  one wave per flagged row, np-bin metric fl32(Zf - fl32(2*dot64))
//             over <=8 candidates, (dq, idx)-lex first-min. [R3/R5/R6-proven]
//   ovf:      full 4096-code rescan, thread-per-code, same np-bin metric.
// Error budget (unchanged from R6, passed absmax 0): screen err 5sigma ~4.4e-5;
// np bin width <= 3.05e-5; EPSQ=40 (1.46e-4) covers with >2x margin. A lane drops
// a window-code only if >=4 land in its 128-code column, in which case all 3
// tracked slots are within thr -> conservatively overflows to full rescan.
typedef __attribute__((ext_vector_type(8))) short bf16x8;
typedef __attribute__((ext_vector_type(4))) float f32x4;

#define DIMD 256
#define KCODES 4096
#define NROWS 32768
#define OUT_LOSS 8388608
#define OUT_IDX  8388609
#define MAXC 8
#define EPSQ 40u              // candidate window in qsteps (40*3.66e-6 = 1.46e-4)
#define QSCALE 273066.67f     // 65536/0.24 : qdist = (dist + 0.12) * QSCALE
#define QBIAS  0.12f

struct CandEntry { int row; int cnt; int codes[MAXC]; };   // 40 B

// ws layout (bytes): loss f32 @0 | wcount i32 @32 | ovfcount i32 @36 |
// clist @4096 (16384 x 40 B) | ovflist @659456 (8192 i32) | Bhi @1MB (2 MB)
#define WS_CLIST 4096u
#define CCAP     16384
#define WS_OVF   659456u
#define OVFCAP   8192
#define WS_BHI   (1024u*1024u)
#define WS_END   (WS_BHI + (unsigned)KCODES*DIMD*2u)   // 3,145,728

__device__ __forceinline__ unsigned short bf16_rne(float f) {
    unsigned u = __float_as_uint(f);
    u += 0x7FFFu + ((u >> 16) & 1u);
    return (unsigned short)(u >> 16);
}

__global__ void init_kernel(float* __restrict__ loss_acc, int* __restrict__ wcount,
                            int* __restrict__ ovfcount) {
    if (threadIdx.x == 0) { loss_acc[0] = 0.0f; wcount[0] = 0; ovfcount[0] = 0; }
}

__global__ __launch_bounds__(256) void convertB_kernel(const float* __restrict__ src,
                                                       unsigned short* __restrict__ hi) {
    const size_t e = ((size_t)blockIdx.x * 256 + threadIdx.x) * 4;
    float4 v = *(const float4*)(src + e);
    ushort4 h;
    h.x = bf16_rne(v.x); h.y = bf16_rne(v.y);
    h.z = bf16_rne(v.z); h.w = bf16_rne(v.w);
    *(ushort4*)(hi + e) = h;
}

__global__ __launch_bounds__(256, 2) void vq_screen_kernel(
        const unsigned short* __restrict__ Bhi,
        const float* __restrict__ x, const float* __restrict__ cb,
        float* __restrict__ out, float* __restrict__ loss_acc,
        int* __restrict__ wcount, CandEntry* __restrict__ clist,
        int* __restrict__ ovfcount, int* __restrict__ ovflist) {
    __shared__ unsigned keys[64 * 97];   // [row][src*3 + slot], stride 97
    __shared__ int   widx[64];
    __shared__ float wpart[4];

    const int tid   = threadIdx.x;
    const int w     = tid >> 6;
    const int lane  = tid & 63;
    const int lanem = lane & 15;
    const int laneq = lane >> 4;
    const int rbase = (w & 1) * 32;      // wave row base (2 row-frags of 16)
    const int cb0   = (w >> 1) * 64;     // wave code-half within each 128-code tile
    const int rb    = blockIdx.x * 64;

    // Persistent A fragments built in-register from fp32 x.
    bf16x8 ah[2][8];
    #pragma unroll
    for (int i = 0; i < 2; ++i) {
        const float* xrow = x + (size_t)(rb + rbase + i * 16 + lanem) * DIMD;
        #pragma unroll
        for (int kc = 0; kc < 8; ++kc) {
            float4 f0 = *(const float4*)(xrow + kc * 32 + laneq * 8);
            float4 f1 = *(const float4*)(xrow + kc * 32 + laneq * 8 + 4);
            bf16x8 v;
            v[0] = (short)bf16_rne(f0.x); v[1] = (short)bf16_rne(f0.y);
            v[2] = (short)bf16_rne(f0.z); v[3] = (short)bf16_rne(f0.w);
            v[4] = (short)bf16_rne(f1.x); v[5] = (short)bf16_rne(f1.y);
            v[6] = (short)bf16_rne(f1.z); v[7] = (short)bf16_rne(f1.w);
            ah[i][kc] = v;
        }
    }

    // Per-lane/slot TOP-3 packed keys.
    unsigned b1[8], b2[8], b3[8];
    #pragma unroll
    for (int s = 0; s < 8; ++s) { b1[s] = 0xFFFFFFFFu; b2[s] = 0xFFFFFFFFu; b3[s] = 0xFFFFFFFFu; }

    // Lane-varying B base: code (cb0+lanem), k-offset laneq*8.
    const unsigned short* Bp = Bhi + (size_t)(cb0 + lanem) * DIMD + laneq * 8;

    for (int ct = 0; ct < KCODES / 128; ++ct) {
        const unsigned short* Bct = Bp + (size_t)ct * 128 * DIMD;
        f32x4 acc[2][4];
        #pragma unroll
        for (int i = 0; i < 2; ++i)
            #pragma unroll
            for (int j = 0; j < 4; ++j)
                acc[i][j] = (f32x4){0.f, 0.f, 0.f, 0.f};

        #pragma unroll
        for (int kc = 0; kc < 8; ++kc) {
            bf16x8 bh[4];
            #pragma unroll
            for (int j = 0; j < 4; ++j)
                bh[j] = *(const bf16x8*)(Bct + j * 16 * DIMD + kc * 32);
            #pragma unroll
            for (int i = 0; i < 2; ++i)
                #pragma unroll
                for (int j = 0; j < 4; ++j)
                    acc[i][j] = __builtin_amdgcn_mfma_f32_16x16x32_bf16(ah[i][kc], bh[j], acc[i][j], 0, 0, 0);
        }
        // key = qdist<<12 | code; branchless sorted top-3 insert (min/max chain).
        #pragma unroll
        for (int j = 0; j < 4; ++j) {
            const unsigned code = (unsigned)(ct * 128 + cb0 + j * 16 + lanem);
            #pragma unroll
            for (int i = 0; i < 2; ++i)
                #pragma unroll
                for (int r = 0; r < 4; ++r) {
                    const int s = i * 4 + r;
                    const float dist = fmaf(acc[i][j][r], -2.0f * QSCALE, QBIAS * QSCALE);
                    const unsigned k = ((unsigned)dist << 12) | code;
                    const unsigned t1 = min(b1[s], k);
                    const unsigned m1 = max(b1[s], k);
                    b1[s] = t1;
                    const unsigned t2 = min(b2[s], m1);
                    const unsigned m2 = max(b2[s], m1);
                    b2[s] = t2;
                    b3[s] = min(b3[s], m2);
                }
        }
    }

    // Merge via LDS (only sync point).
    {
        const int src = (w >> 1) * 16 + lanem;   // 0..31 columns per row
        #pragma unroll
        for (int i = 0; i < 2; ++i)
            #pragma unroll
            for (int r = 0; r < 4; ++r) {
                const int s = i * 4 + r;
                const int rr = rbase + i * 16 + laneq * 4 + r;
                keys[rr * 97 + src * 3 + 0] = b1[s];
                keys[rr * 97 + src * 3 + 1] = b2[s];
                keys[rr * 97 + src * 3 + 2] = b3[s];
            }
    }
    __syncthreads();
    if (tid < 64) {
        const int base = tid * 97;
        unsigned kmin = 0xFFFFFFFFu;
        for (int t = 0; t < 96; ++t) kmin = min(kmin, keys[base + t]);
        const unsigned thr = (((kmin >> 12) + EPSQ) << 12) | 0xFFFu;
        int cand[MAXC]; int nc = 0; int ovf = 0;
        for (int L = 0; L < 32; ++L) {
            const unsigned v0 = keys[base + L * 3 + 0];
            if (v0 <= thr) {
                if (nc < MAXC) cand[nc] = (int)(v0 & 0xFFFu);
                ++nc;
                const unsigned v1 = keys[base + L * 3 + 1];
                if (v1 <= thr) {
                    if (nc < MAXC) cand[nc] = (int)(v1 & 0xFFFu);
                    ++nc;
                    const unsigned v2 = keys[base + L * 3 + 2];
                    if (v2 <= thr) {      // lane's 4th-best unknown -> conservative
                        if (nc < MAXC) cand[nc] = (int)(v2 & 0xFFFu);
                        ++nc;
                        ovf = 1;
                    }
                }
            }
        }
        const int row = rb + tid;
        const int bi = (int)(kmin & 0xFFFu);
        widx[tid] = bi;
        out[OUT_IDX + (size_t)row] = (float)bi;
        if (ovf || nc > MAXC) {
            const int op = atomicAdd(ovfcount, 1);
            if (op < OVFCAP) ovflist[op] = row;
        } else if (nc >= 2) {
            const int pos = atomicAdd(wcount, 1);
            if (pos < CCAP) {
                CandEntry* e = &clist[pos];
                e->row = row; e->cnt = nc;
                for (int q = 0; q < nc; ++q) e->codes[q] = cand[q];
            } else {
                const int op = atomicAdd(ovfcount, 1);
                if (op < OVFCAP) ovflist[op] = row;
            }
        }
    }
    __syncthreads();

    // Gather z_q, write z_q_st = x + (z_q - x), accumulate loss partial.
    float lsum = 0.0f;
    const int dv = (tid & 63) * 4;
    const int rs = tid >> 6;
    const float* xblk = x + (size_t)rb * DIMD;
    float* oblk = out + (size_t)rb * DIMD;
    for (int p = 0; p < 16; ++p) {
        const int row = p * 4 + rs;
        const int wi = widx[row];
        float4 xv = *(const float4*)(xblk + (size_t)row * DIMD + dv);
        float4 cv = *(const float4*)(cb + (size_t)wi * DIMD + dv);
        const float d0 = cv.x - xv.x, d1 = cv.y - xv.y, d2 = cv.z - xv.z, d3 = cv.w - xv.w;
        float4 o;
        o.x = xv.x + d0; o.y = xv.y + d1; o.z = xv.z + d2; o.w = xv.w + d3;
        *(float4*)(oblk + (size_t)row * DIMD + dv) = o;
        lsum += d0 * d0 + d1 * d1 + d2 * d2 + d3 * d3;
    }
    #pragma unroll
    for (int off = 32; off > 0; off >>= 1) lsum += __shfl_down(lsum, off, 64);
    if ((tid & 63) == 0) wpart[tid >> 6] = lsum;
    __syncthreads();
    if (tid == 0) atomicAdd(loss_acc, wpart[0] + wpart[1] + wpart[2] + wpart[3]);
}

// One wave per flagged row; np-bin metric over <=8 candidates. [R5/R6-proven]
__global__ __launch_bounds__(256) void vq_candfix_kernel(
        const float* __restrict__ x, const float* __restrict__ cb,
        float* __restrict__ out, float* __restrict__ loss_acc,
        const int* __restrict__ wcount, const CandEntry* __restrict__ clist) {
    int count = wcount[0];
    if (count > CCAP) count = CCAP;
    const int lane = threadIdx.x & 63;
    const int gw = blockIdx.x * 4 + (threadIdx.x >> 6);
    const int nw = gridDim.x * 4;
    for (int it = gw; it < count; it += nw) {
        const CandEntry* e = clist + it;
        const int row = e->row;
        const int cnt = e->cnt;
        const float4 xv = *(const float4*)(x + (size_t)row * DIMD + lane * 4);
        double zs = (double)xv.x * xv.x + (double)xv.y * xv.y
                  + (double)xv.z * xv.z + (double)xv.w * xv.w;
        #pragma unroll
        for (int off = 32; off > 0; off >>= 1) zs += __shfl_xor(zs, off, 64);
        const float Zf = (float)zs;   // grid-aligned z_sq (translation-invariance)
        float bq = 3.4e38f; int bi = 0x7fffffff;
        for (int q = 0; q < cnt; ++q) {
            const int c = e->codes[q];
            const float4 cv = *(const float4*)(cb + (size_t)c * DIMD + lane * 4);
            double dp = (double)xv.x * cv.x + (double)xv.y * cv.y
                      + (double)xv.z * cv.z + (double)xv.w * cv.w;
            #pragma unroll
            for (int off = 32; off > 0; off >>= 1) dp += __shfl_xor(dp, off, 64);
            const float wv = (float)(2.0 * dp);
            const float dq = Zf - wv;             // fp32 subtract = np's bin
            if (dq < bq || (dq == bq && c < bi)) { bq = dq; bi = c; }
        }
        const int oldi = (int)out[OUT_IDX + (size_t)row];
        if (bi != oldi) {
            const float4 cn = *(const float4*)(cb + (size_t)bi * DIMD + lane * 4);
            const float4 co = *(const float4*)(cb + (size_t)oldi * DIMD + lane * 4);
            float4 o; float ls = 0.0f;
            { const float dn = cn.x - xv.x, dd = co.x - xv.x; o.x = xv.x + dn; ls += dn*dn - dd*dd; }
            { const float dn = cn.y - xv.y, dd = co.y - xv.y; o.y = xv.y + dn; ls += dn*dn - dd*dd; }
            { const float dn = cn.z - xv.z, dd = co.z - xv.z; o.z = xv.z + dn; ls += dn*dn - dd*dd; }
            { const float dn = cn.w - xv.w, dd = co.w - xv.w; o.w = xv.w + dn; ls += dn*dn - dd*dd; }
            *(float4*)(out + (size_t)row * DIMD + lane * 4) = o;
            #pragma unroll
            for (int off = 32; off > 0; off >>= 1) ls += __shfl_xor(ls, off, 64);
            if (lane == 0) {
                atomicAdd(loss_acc, ls);
                out[OUT_IDX + (size_t)row] = (float)bi;
            }
        }
    }
}

// Overflow rows: full 4096-code rescan, thread-per-code, np-bin metric.
__global__ __launch_bounds__(256) void vq_ovf_kernel(
        const float* __restrict__ x, const float* __restrict__ cb,
        float* __restrict__ out, float* __restrict__ loss_acc,
        const int* __restrict__ ovfcount, const int* __restrict__ ovflist) {
    __shared__ double xd[DIMD];
    __shared__ double zred[256];
    __shared__ float  rdq[256];
    __shared__ int    ri[256];
    __shared__ float  lred[256];
    const int tid = threadIdx.x;
    int count = ovfcount[0];
    if (count > OVFCAP) count = OVFCAP;
    for (int item = blockIdx.x; item < count; item += gridDim.x) {
        const int row = ovflist[item];
        const double xv0 = (double)x[(size_t)row * DIMD + tid];
        xd[tid] = xv0;
        zred[tid] = xv0 * xv0;
        __syncthreads();
        for (int st = 128; st > 0; st >>= 1) {
            if (tid < st) zred[tid] += zred[tid + st];
            __syncthreads();
        }
        const float Zf = (float)zred[0];
        float bq = 3.4e38f; int bi = 0x7fffffff;
        for (int q = 0; q < 16; ++q) {
            const int c = q * 256 + tid;
            const float* cr = cb + (size_t)c * DIMD;
            double s = 0.0;
            for (int d = 0; d < DIMD; d += 4) {
                float4 cv = *(const float4*)(cr + d);
                s += xd[d + 0] * (double)cv.x + xd[d + 1] * (double)cv.y
                   + xd[d + 2] * (double)cv.z + xd[d + 3] * (double)cv.w;
            }
            const float wv = (float)(2.0 * s);
            const float dq = Zf - wv;
            if (dq < bq || (dq == bq && c < bi)) { bq = dq; bi = c; }
        }
        rdq[tid] = bq; ri[tid] = bi;
        __syncthreads();
        for (int st = 128; st > 0; st >>= 1) {
            if (tid < st) {
                const float oq = rdq[tid + st]; const int oi = ri[tid + st];
                if (oq < rdq[tid] || (oq == rdq[tid] && oi < ri[tid])) {
                    rdq[tid] = oq; ri[tid] = oi;
                }
            }
            __syncthreads();
        }
        const int newi = ri[0];
        const int oldi = (int)out[OUT_IDX + (size_t)row];
        if (newi != oldi) {
            const float xv = x[(size_t)row * DIMD + tid];
            const float co = cb[(size_t)oldi * DIMD + tid];
            const float cn = cb[(size_t)newi * DIMD + tid];
            const float dold = co - xv, dnew = cn - xv;
            out[(size_t)row * DIMD + tid] = xv + dnew;
            lred[tid] = dnew * dnew - dold * dold;
        } else {
            lred[tid] = 0.0f;
        }
        __syncthreads();
        for (int st = 128; st > 0; st >>= 1) {
            if (tid < st) lred[tid] += lred[tid + st];
            __syncthreads();
        }
        if (tid == 0 && newi != oldi) {
            atomicAdd(loss_acc, lred[0]);
            out[OUT_IDX + (size_t)row] = (float)newi;
        }
        __syncthreads();
    }
}

__global__ void finalize_kernel(const float* __restrict__ loss_acc, float* __restrict__ out) {
    if (threadIdx.x == 0 && blockIdx.x == 0)
        out[OUT_LOSS] = 1.25f * (loss_acc[0] / 8388608.0f);
}

// ===== fallback fp32 path (R3-proven) for small ws_size =====
#define MT 128
#define DK 32
#define LSTR 130
#define FLAG_EPS_F32 3.6e-5f
__global__ __launch_bounds__(256) void vq_main_fp32_kernel(const float* __restrict__ x,
                                                           const float* __restrict__ cb,
                                                           float* __restrict__ out,
                                                           float* __restrict__ loss_acc,
                                                           int* __restrict__ wcount,
                                                           int* __restrict__ wlist,
                                                           int wcap) {
    __shared__ float As[DK * LSTR];
    __shared__ float Bs[DK * LSTR];
    __shared__ float red_d[MT * 17];
    __shared__ float red_2[MT * 17];
    __shared__ int   red_i[MT * 17];
    __shared__ int   widx[MT];
    __shared__ float wpart[4];
    const int tid = threadIdx.x;
    const int tx = tid & 15;
    const int ty = tid >> 4;
    const float* xblk = x + (size_t)blockIdx.x * MT * DIMD;
    float b1[8], b2[8]; int i1[8];
    #pragma unroll
    for (int i = 0; i < 8; ++i) { b1[i] = 3.4e38f; b2[i] = 3.4e38f; i1[i] = 0; }
    const int sr = tid >> 3;
    const int sd = (tid & 7) * 4;
    for (int kt = 0; kt < KCODES; kt += 128) {
        float acc[8][8];
        #pragma unroll
        for (int i = 0; i < 8; ++i)
            #pragma unroll
            for (int j = 0; j < 8; ++j) acc[i][j] = 0.0f;
        const float* bblk = cb + (size_t)kt * DIMD;
        for (int dc = 0; dc < DIMD; dc += DK) {
            __syncthreads();
            #pragma unroll
            for (int p = 0; p < 4; ++p) {
                const int r = p * 32 + sr;
                float4 va = *(const float4*)(xblk + (size_t)r * DIMD + dc + sd);
                float4 vb = *(const float4*)(bblk + (size_t)r * DIMD + dc + sd);
                As[(sd + 0) * LSTR + r] = va.x; As[(sd + 1) * LSTR + r] = va.y;
                As[(sd + 2) * LSTR + r] = va.z; As[(sd + 3) * LSTR + r] = va.w;
                Bs[(sd + 0) * LSTR + r] = vb.x; Bs[(sd + 1) * LSTR + r] = vb.y;
                Bs[(sd + 2) * LSTR + r] = vb.z; Bs[(sd + 3) * LSTR + r] = vb.w;
            }
            __syncthreads();
            #pragma unroll 4
            for (int d = 0; d < DK; ++d) {
                const float2* ap = (const float2*)&As[d * LSTR + ty * 8];
                const float2* bp = (const float2*)&Bs[d * LSTR + tx * 8];
                float2 a0 = ap[0], a1 = ap[1], a2 = ap[2], a3 = ap[3];
                float2 c0 = bp[0], c1 = bp[1], c2 = bp[2], c3 = bp[3];
                float a[8] = {a0.x, a0.y, a1.x, a1.y, a2.x, a2.y, a3.x, a3.y};
                float b[8] = {c0.x, c0.y, c1.x, c1.y, c2.x, c2.y, c3.x, c3.y};
                #pragma unroll
                for (int i = 0; i < 8; ++i)
                    #pragma unroll
                    for (int j = 0; j < 8; ++j)
                        acc[i][j] += a[i] * b[j];
            }
        }
        #pragma unroll
        for (int j = 0; j < 8; ++j) {
            const int code = kt + tx * 8 + j;
            #pragma unroll
            for (int i = 0; i < 8; ++i) {
                const float dist = -(acc[i][j] + acc[i][j]);
                if (dist < b1[i]) { b2[i] = b1[i]; b1[i] = dist; i1[i] = code; }
                else if (dist < b2[i]) b2[i] = dist;
            }
        }
    }
    __syncthreads();
    #pragma unroll
    for (int i = 0; i < 8; ++i) {
        red_d[(ty * 8 + i) * 17 + tx] = b1[i];
        red_2[(ty * 8 + i) * 17 + tx] = b2[i];
        red_i[(ty * 8 + i) * 17 + tx] = i1[i];
    }
    __syncthreads();
    if (tid < MT) {
        float bd = red_d[tid * 17];
        float s2 = red_2[tid * 17];
        int   bi = red_i[tid * 17];
        #pragma unroll
        for (int t = 1; t < 16; ++t) {
            const float d1 = red_d[tid * 17 + t];
            const float d2 = red_2[tid * 17 + t];
            const int   ii = red_i[tid * 17 + t];
            if (d1 < bd || (d1 == bd && ii < bi)) { s2 = fminf(bd, d2); bd = d1; bi = ii; }
            else s2 = fminf(s2, d1);
        }
        const int row = blockIdx.x * MT + tid;
        widx[tid] = bi;
        out[OUT_IDX + (size_t)row] = (float)bi;
        if (s2 - bd <= FLAG_EPS_F32) {
            const int pos = atomicAdd(wcount, 1);
            if (pos < wcap) wlist[pos] = row;
        }
    }
    __syncthreads();
    float lsum = 0.0f;
    const int dv = (tid & 63) * 4;
    const int rs = tid >> 6;
    float* oblk = out + (size_t)blockIdx.x * MT * DIMD;
    for (int p = 0; p < 32; ++p) {
        const int row = p * 4 + rs;
        const int wi = widx[row];
        float4 xv = *(const float4*)(xblk + (size_t)row * DIMD + dv);
        float4 cv = *(const float4*)(cb + (size_t)wi * DIMD + dv);
        const float d0 = cv.x - xv.x, d1 = cv.y - xv.y, d2 = cv.z - xv.z, d3 = cv.w - xv.w;
        float4 o;
        o.x = xv.x + d0; o.y = xv.y + d1; o.z = xv.z + d2; o.w = xv.w + d3;
        *(float4*)(oblk + (size_t)row * DIMD + dv) = o;
        lsum += d0 * d0 + d1 * d1 + d2 * d2 + d3 * d3;
    }
    #pragma unroll
    for (int off = 32; off > 0; off >>= 1) lsum += __shfl_down(lsum, off, 64);
    if ((tid & 63) == 0) wpart[tid >> 6] = lsum;
    __syncthreads();
    if (tid == 0) atomicAdd(loss_acc, wpart[0] + wpart[1] + wpart[2] + wpart[3]);
}

extern "C" void kernel_launch(void* const* d_in, const int* in_sizes, int n_in,
                              void* d_out, int out_size, void* d_ws, size_t ws_size,
                              hipStream_t stream) {
    const float* x  = (const float*)d_in[0];
    const float* cb = (const float*)d_in[1];
    float* out = (float*)d_out;
    float* loss_acc = (float*)d_ws;
    int*   wcount   = (int*)((char*)d_ws + 32);
    int*   ovfcount = (int*)((char*)d_ws + 36);
    CandEntry* clist = (CandEntry*)((char*)d_ws + WS_CLIST);
    int*   ovflist  = (int*)((char*)d_ws + WS_OVF);

    init_kernel<<<1, 64, 0, stream>>>(loss_acc, wcount, ovfcount);
    if (ws_size >= (size_t)WS_END) {
        unsigned short* Bhi = (unsigned short*)((char*)d_ws + WS_BHI);
        convertB_kernel<<<1024, 256, 0, stream>>>(cb, Bhi);
        vq_screen_kernel<<<512, 256, 0, stream>>>(Bhi, x, cb, out, loss_acc,
                                                  wcount, clist, ovfcount, ovflist);
        vq_candfix_kernel<<<512, 256, 0, stream>>>(x, cb, out, loss_acc, wcount, clist);
        vq_ovf_kernel<<<256, 256, 0, stream>>>(x, cb, out, loss_acc, ovfcount, ovflist);
    } else {
        int* wlist = (int*)((char*)d_ws + WS_CLIST);
        int wcap = 0;
        if (ws_size > WS_CLIST + sizeof(int)) {
            size_t c = (ws_size - WS_CLIST) / sizeof(int);
            wcap = (int)(c > 32768 ? 32768 : c);
        }
        vq_main_fp32_kernel<<<256, 256, 0, stream>>>(x, cb, out, loss_acc,
                                                     wcount, wlist, wcap);
        vq_ovf_kernel<<<512, 256, 0, stream>>>(x, cb, out, loss_acc, wcount, wlist);
    }
    finalize_kernel<<<1, 1, 0, stream>>>(loss_acc, out);
}